// Round 7
// baseline (249.120 us; speedup 1.0000x reference)
//
#include <hip/hip_runtime.h>
#include <math.h>

// Problem dims (fixed)
#define B_   128
#define L_   256
#define H_   128
#define H2_  256
#define VS_  256
#define TOK_ (B_ * L_)   // 32768

__device__ __forceinline__ float fma4(float4 a, float4 b, float acc) {
    acc = fmaf(a.x, b.x, acc);
    acc = fmaf(a.y, b.y, acc);
    acc = fmaf(a.z, b.z, acc);
    acc = fmaf(a.w, b.w, acc);
    return acc;
}

// ---------------- DPP cross-lane helpers (VALU-latency, no LDS) -------------
template <int CTRL>
__device__ __forceinline__ float dpp_add(float x) {
    int y = __builtin_amdgcn_update_dpp(0, __float_as_int(x), CTRL, 0xf, 0xf, true);
    return x + __int_as_float(y);
}
// Full 64-lane sum; total lands in lane 63.
__device__ __forceinline__ float wave_sum(float x) {
    x = dpp_add<0x111>(x);  // row_shr:1
    x = dpp_add<0x112>(x);  // row_shr:2
    x = dpp_add<0x114>(x);  // row_shr:4
    x = dpp_add<0x118>(x);  // row_shr:8
    x = dpp_add<0x142>(x);  // row_bcast:15
    x = dpp_add<0x143>(x);  // row_bcast:31
    return x;
}
// Sum over the 4 lanes of each quad (butterfly -> valid in all 4 lanes).
__device__ __forceinline__ float quad_sum(float x) {
    x = dpp_add<0xB1>(x);   // quad_perm [1,0,3,2]
    x = dpp_add<0x4E>(x);   // quad_perm [2,3,0,1]
    return x;
}

// LDS index swizzles for k_ffn (unchanged)
#define HIDX(row, c4) ((row) * 32 + ((c4) ^ (((row) >> 2) & 7)))
#define WIDX(oc, k4)  ((oc) * 16 + ((k4) ^ (((oc) >> 2) & 15)))
#define YIDX(row, y4) ((row) * 16 + ((y4) ^ (((row) >> 2) & 15)))

// ---------------------------------------------------------------------------
// Kernel 1: fused  h = embed[seq];  f = relu(h@W1^T+b1)@W2^T+b2;
//                  x = h+f;  hln = LN(x)*gamma+beta;  K = hln@Wk^T
// (unchanged from round 1)
// ---------------------------------------------------------------------------
__global__ __launch_bounds__(256, 2) void k_ffn(
    const int* __restrict__ seq, const float* __restrict__ embed,
    const float* __restrict__ W1, const float* __restrict__ b1,
    const float* __restrict__ W2, const float* __restrict__ b2,
    const float* __restrict__ gamma, const float* __restrict__ beta,
    const float* __restrict__ Wk, float* __restrict__ Kout)
{
    __shared__ float4 sh_h[64 * 32];
    __shared__ float4 sh_w[64 * 16];
    __shared__ float4 sh_y[64 * 16];

    const int tid  = threadIdx.x;
    const int tc   = tid & 15;
    const int tr   = tid >> 4;
    const int tok0 = blockIdx.x * 64;

    const float4* embed4 = (const float4*)embed;
    const float4* W1_4   = (const float4*)W1;
    const float4* W2_4   = (const float4*)W2;
    const float4* Wk_4   = (const float4*)Wk;
    const float4* b1_4   = (const float4*)b1;
    const float4* b2_4   = (const float4*)b2;
    const float4* g_4    = (const float4*)gamma;
    const float4* be_4   = (const float4*)beta;

    #pragma unroll
    for (int f = tid; f < 2048; f += 256) {
        int row = f >> 5, c4 = f & 31;
        int idx = seq[tok0 + row];
        sh_h[HIDX(row, c4)] = embed4[idx * 32 + c4];
    }
    __syncthreads();

    float xacc[4][2][4];
    #pragma unroll
    for (int i = 0; i < 4; ++i)
        #pragma unroll
        for (int xh = 0; xh < 2; ++xh)
            #pragma unroll
            for (int j = 0; j < 4; ++j) xacc[i][xh][j] = 0.f;

    for (int nt = 0; nt < 4; ++nt) {
        float acc1[4][4];
        #pragma unroll
        for (int i = 0; i < 4; ++i)
            #pragma unroll
            for (int j = 0; j < 4; ++j) acc1[i][j] = 0.f;

        for (int kt = 0; kt < 2; ++kt) {
            #pragma unroll
            for (int f = tid; f < 1024; f += 256) {
                int oc = f >> 4, k4 = f & 15;
                sh_w[WIDX(oc, k4)] = W1_4[(nt * 64 + oc) * 32 + kt * 16 + k4];
            }
            __syncthreads();
            #pragma unroll 4
            for (int k4i = 0; k4i < 16; ++k4i) {
                float4 a4[4], b4[4];
                #pragma unroll
                for (int i = 0; i < 4; ++i) a4[i] = sh_h[HIDX(tr * 4 + i, kt * 16 + k4i)];
                #pragma unroll
                for (int j = 0; j < 4; ++j) b4[j] = sh_w[WIDX(tc * 4 + j, k4i)];
                #pragma unroll
                for (int i = 0; i < 4; ++i)
                    #pragma unroll
                    for (int j = 0; j < 4; ++j) acc1[i][j] = fma4(a4[i], b4[j], acc1[i][j]);
            }
            __syncthreads();
        }
        {
            float4 bv = b1_4[nt * 16 + tc];
            #pragma unroll
            for (int i = 0; i < 4; ++i) {
                float4 y;
                y.x = fmaxf(acc1[i][0] + bv.x, 0.f);
                y.y = fmaxf(acc1[i][1] + bv.y, 0.f);
                y.z = fmaxf(acc1[i][2] + bv.z, 0.f);
                y.w = fmaxf(acc1[i][3] + bv.w, 0.f);
                sh_y[YIDX(tr * 4 + i, tc)] = y;
            }
        }
        __syncthreads();

        #pragma unroll
        for (int xh = 0; xh < 2; ++xh) {
            #pragma unroll
            for (int f = tid; f < 1024; f += 256) {
                int oc = f >> 4, y4 = f & 15;
                sh_w[WIDX(oc, y4)] = W2_4[(xh * 64 + oc) * 64 + nt * 16 + y4];
            }
            __syncthreads();
            #pragma unroll 4
            for (int y4i = 0; y4i < 16; ++y4i) {
                float4 a4[4], b4[4];
                #pragma unroll
                for (int i = 0; i < 4; ++i) a4[i] = sh_y[YIDX(tr * 4 + i, y4i)];
                #pragma unroll
                for (int j = 0; j < 4; ++j) b4[j] = sh_w[WIDX(tc * 4 + j, y4i)];
                #pragma unroll
                for (int i = 0; i < 4; ++i)
                    #pragma unroll
                    for (int j = 0; j < 4; ++j) xacc[i][xh][j] = fma4(a4[i], b4[j], xacc[i][xh][j]);
            }
            __syncthreads();
        }
    }

    #pragma unroll
    for (int xh = 0; xh < 2; ++xh) {
        float4 bv = b2_4[xh * 16 + tc];
        int c4 = xh * 16 + tc;
        #pragma unroll
        for (int i = 0; i < 4; ++i) {
            float4 h4 = sh_h[HIDX(tr * 4 + i, c4)];
            h4.x += xacc[i][xh][0] + bv.x;
            h4.y += xacc[i][xh][1] + bv.y;
            h4.z += xacc[i][xh][2] + bv.z;
            h4.w += xacc[i][xh][3] + bv.w;
            sh_h[HIDX(tr * 4 + i, c4)] = h4;
        }
    }
    __syncthreads();

    {
        int row = tid >> 2, q = tid & 3;
        float s = 0.f, s2 = 0.f;
        #pragma unroll
        for (int u = 0; u < 8; ++u) {
            float4 v = sh_h[HIDX(row, q * 8 + u)];
            s  += v.x + v.y + v.z + v.w;
            s2 += v.x * v.x + v.y * v.y + v.z * v.z + v.w * v.w;
        }
        s  += __shfl_xor(s, 1);  s  += __shfl_xor(s, 2);
        s2 += __shfl_xor(s2, 1); s2 += __shfl_xor(s2, 2);
        float mu   = s * (1.f / 128.f);
        float var  = s2 * (1.f / 128.f) - mu * mu;
        float rstd = 1.f / sqrtf(var + 1e-5f);
        #pragma unroll
        for (int u = 0; u < 8; ++u) {
            int c4 = q * 8 + u;
            float4 v  = sh_h[HIDX(row, c4)];
            float4 gv = g_4[c4], bev = be_4[c4];
            v.x = (v.x - mu) * rstd * gv.x + bev.x;
            v.y = (v.y - mu) * rstd * gv.y + bev.y;
            v.z = (v.z - mu) * rstd * gv.z + bev.z;
            v.w = (v.w - mu) * rstd * gv.w + bev.w;
            sh_h[HIDX(row, c4)] = v;
        }
    }
    __syncthreads();

    for (int ch = 0; ch < 2; ++ch) {
        float acc[4][4];
        #pragma unroll
        for (int i = 0; i < 4; ++i)
            #pragma unroll
            for (int j = 0; j < 4; ++j) acc[i][j] = 0.f;

        for (int kt = 0; kt < 2; ++kt) {
            #pragma unroll
            for (int f = tid; f < 1024; f += 256) {
                int oc = f >> 4, k4 = f & 15;
                sh_w[WIDX(oc, k4)] = Wk_4[(ch * 64 + oc) * 32 + kt * 16 + k4];
            }
            __syncthreads();
            #pragma unroll 4
            for (int k4i = 0; k4i < 16; ++k4i) {
                float4 a4[4], b4[4];
                #pragma unroll
                for (int i = 0; i < 4; ++i) a4[i] = sh_h[HIDX(tr * 4 + i, kt * 16 + k4i)];
                #pragma unroll
                for (int j = 0; j < 4; ++j) b4[j] = sh_w[WIDX(tc * 4 + j, k4i)];
                #pragma unroll
                for (int i = 0; i < 4; ++i)
                    #pragma unroll
                    for (int j = 0; j < 4; ++j) acc[i][j] = fma4(a4[i], b4[j], acc[i][j]);
            }
            __syncthreads();
        }
        #pragma unroll
        for (int i = 0; i < 4; ++i) {
            float4 o = make_float4(acc[i][0], acc[i][1], acc[i][2], acc[i][3]);
            ((float4*)Kout)[(tok0 + tr * 4 + i) * 32 + ch * 16 + tc] = o;
        }
    }
}

// ---------------------------------------------------------------------------
// Kernel 2: gated delta-rule scan — 2 steps per barrier.
//   Region R (steps T=2R, T+1): pre-barrier {deferred M updates for T-2,T-1;
//   matvecs M_T·k_{T+1}, M_T·k_{T+2}; reduce e2(err_T), e2(errA), errA·err_T}
//   one barrier; post-barrier both gates resolve algebraically:
//     err_{T+1} = errA − g_T·c·err_T,  c = rna[T+1]·rc[T]
//     e2(err_{T+1}|g=1) = e2A − 2c·cross + c²·e2T
//     dot_{T+2} = pre1 + g_T·rc2[T]·err_T + g_{T+1}·rc[T+1]·err_{T+1}
//   M updates deferred to next region (operands in 4 rotating reg k-buffers,
//   ALL statically indexed; gates branch block-uniform on cu≠0).
// ---------------------------------------------------------------------------
__global__ __launch_bounds__(256, 1) void k_scan(
    const float* __restrict__ Kbuf, float* __restrict__ readout)
{
    extern __shared__ float smem_f[];
    float4* shk4 = (float4*)smem_f;          // [256][32] float4 = 128 KiB
    float*  rna  = smem_f + 32768;           // [256] 1/max(||k_t||,eps)
    float*  thr  = rna + 256;                // [256] 0.16*||k_t||^2
    float*  rc_  = thr + 256;                // [256] rna[t]*(k_t . k_{t+1})
    float*  rc2  = rc_ + 256;                // [256] rna[t]*(k_t . k_{t+2})
    float4* red4 = (float4*)(rc2 + 256);     // [2][4]

    const int tid  = threadIdx.x;
    const int lane = tid & 63;
    const int w    = tid >> 6;        // wave id 0..3
    const int cq   = lane & 3;        // col chunk 0..3 (32 cols each)
    const int p    = lane >> 2;       // row pair 0..15
    const int b    = blockIdx.x;
    const float4* K4 = (const float4*)Kbuf;
    const size_t base32 = (size_t)b * 256 * 32;

    // ---- prologue 1: stage ALL k vectors ----
    for (int f = tid; f < 8192; f += 256) shk4[f] = K4[base32 + f];
    __syncthreads();

    // ---- prologue 2: per-row norms + neighbor dots (16 threads per row) ----
    {
        int rr = tid >> 4, cc = tid & 15;
        for (int it = 0; it < 16; ++it) {
            int t   = it * 16 + rr;
            int tn  = (t < 255) ? t + 1 : 255;
            int tn2 = (t < 254) ? t + 2 : 255;
            float4 a0 = shk4[t   * 32 + cc], a1 = shk4[t   * 32 + 16 + cc];
            float4 b0 = shk4[tn  * 32 + cc], b1 = shk4[tn  * 32 + 16 + cc];
            float4 c0 = shk4[tn2 * 32 + cc], c1 = shk4[tn2 * 32 + 16 + cc];
            float n2p = fma4(a1, a1, fma4(a0, a0, 0.f));
            float cp  = fma4(a1, b1, fma4(a0, b0, 0.f));
            float cp2 = fma4(a1, c1, fma4(a0, c0, 0.f));
            n2p += __shfl_xor(n2p, 1); n2p += __shfl_xor(n2p, 2);
            n2p += __shfl_xor(n2p, 4); n2p += __shfl_xor(n2p, 8);
            cp  += __shfl_xor(cp, 1);  cp  += __shfl_xor(cp, 2);
            cp  += __shfl_xor(cp, 4);  cp  += __shfl_xor(cp, 8);
            cp2 += __shfl_xor(cp2, 1); cp2 += __shfl_xor(cp2, 2);
            cp2 += __shfl_xor(cp2, 4); cp2 += __shfl_xor(cp2, 8);
            if (cc == 0) {
                float ri = 1.f / fmaxf(sqrtf(n2p), 1e-12f);
                rna[t] = ri;
                thr[t] = 0.16f * n2p;
                rc_[t] = ri * cp;
                rc2[t] = ri * cp2;
            }
        }
    }
    __syncthreads();

    // M rows {w*32+2p, w*32+2p+1}, cols cq*32..+31 (labeling rotated by cq).
    float4 m0[8], m1[8];
    float4 kbA[8], kbB[8], kbC[8], kbD[8];
    #pragma unroll
    for (int u = 0; u < 8; ++u) {
        m0[u] = make_float4(0.f, 0.f, 0.f, 0.f);
        m1[u] = make_float4(0.f, 0.f, 0.f, 0.f);
        kbA[u] = m0[u]; kbB[u] = m0[u]; kbC[u] = m0[u];
    }
    {   // k_0 -> kbD (update operand for region T=2)
        const float4* ks = shk4 + cq * 8;
        #pragma unroll
        for (int u = 0; u < 8; ++u) kbD[u] = ks[(u + cq) & 7];
    }
    float2 k0s = ((const float2*)shk4)[w * 16 + p];
    float errC0 = k0s.x, errC1 = k0s.y;   // err_0 = k_0
    float errP0 = 0.f, errP1 = 0.f, errQ0 = 0.f, errQ1 = 0.f;
    float cuP = 0.f, cuQ = 0.f;

#define UPD(CU, E0, E1, KB)                                                     \
    if ((CU) != 0.f) {                                                          \
      float a0_ = (CU) * (E0), a1_ = (CU) * (E1);                               \
      _Pragma("unroll")                                                         \
      for (int u = 0; u < 8; ++u) {                                             \
        m0[u].x = fmaf(a0_, KB[u].x, m0[u].x);                                  \
        m0[u].y = fmaf(a0_, KB[u].y, m0[u].y);                                  \
        m0[u].z = fmaf(a0_, KB[u].z, m0[u].z);                                  \
        m0[u].w = fmaf(a0_, KB[u].w, m0[u].w);                                  \
        m1[u].x = fmaf(a1_, KB[u].x, m1[u].x);                                  \
        m1[u].y = fmaf(a1_, KB[u].y, m1[u].y);                                  \
        m1[u].z = fmaf(a1_, KB[u].z, m1[u].z);                                  \
        m1[u].w = fmaf(a1_, KB[u].w, m1[u].w);                                  \
      }                                                                         \
    }

#define REGION2(T, UP, UQ, NX, NY)                                              \
  {                                                                             \
    const int t_  = (T);                                                        \
    const int par = (t_ >> 1) & 1;                                              \
    float rnT  = rna[t_], rnT1 = rna[t_ + 1], rnT2 = rna[t_ + 2];               \
    float thrT = thr[t_], thrT1 = thr[t_ + 1];                                  \
    float rcT  = rc_[t_], rcT1 = rc_[t_ + 1], rc2T = rc2[t_];                   \
    /* load NX = k_{T+1} early (hides LDS latency under update FMAs) */         \
    {                                                                           \
      const float4* ks = shk4 + (t_ + 1) * 32 + cq * 8;                         \
      _Pragma("unroll")                                                         \
      for (int u = 0; u < 8; ++u) NX[u] = ks[(u + cq) & 7];                     \
    }                                                                           \
    float2 ks1 = ((const float2*)(shk4 + (t_ + 1) * 32))[w * 16 + p];           \
    float2 ks2 = ((const float2*)(shk4 + (t_ + 2) * 32))[w * 16 + p];           \
    /* deferred updates for steps T-2 (UP) and T-1 (UQ) */                      \
    UPD(cuP, errP0, errP1, UP)                                                  \
    UPD(cuQ, errQ0, errQ1, UQ)                                                  \
    /* load NY = k_{T+2} AFTER updates (NY may alias UP) */                     \
    {                                                                           \
      const float4* ks = shk4 + (t_ + 2) * 32 + cq * 8;                         \
      _Pragma("unroll")                                                         \
      for (int u = 0; u < 8; ++u) NY[u] = ks[(u + cq) & 7];                     \
    }                                                                           \
    /* matvecs with M_T */                                                      \
    float p0a = 0.f, p0b = 0.f, p1a = 0.f, p1b = 0.f;                           \
    _Pragma("unroll")                                                           \
    for (int u = 0; u < 8; ++u) {                                               \
      p0a = fma4(m0[u], NX[u], p0a); p0b = fma4(m1[u], NX[u], p0b);             \
      p1a = fma4(m0[u], NY[u], p1a); p1b = fma4(m1[u], NY[u], p1b);             \
    }                                                                           \
    p0a = quad_sum(p0a); p0b = quad_sum(p0b);                                   \
    p1a = quad_sum(p1a); p1b = quad_sum(p1b);                                   \
    float eA0 = ks1.x - rnT1 * p0a, eA1 = ks1.y - rnT1 * p0b;                   \
    float e2c = 0.f, e2a = 0.f, crs = 0.f;                                      \
    if (cq == 0) {                                                              \
      e2c = fmaf(errC0, errC0, errC1 * errC1);                                  \
      e2a = fmaf(eA0, eA0, eA1 * eA1);                                          \
      crs = fmaf(eA0, errC0, eA1 * errC1);                                      \
    }                                                                           \
    e2c = wave_sum(e2c); e2a = wave_sum(e2a); crs = wave_sum(crs);              \
    if (lane == 63) red4[par * 4 + w] = make_float4(e2c, e2a, crs, 0.f);        \
    __syncthreads();                                                            \
    float4 r0 = red4[par * 4 + 0], r1 = red4[par * 4 + 1];                      \
    float4 r2 = red4[par * 4 + 2], r3 = red4[par * 4 + 3];                      \
    float E2C = (r0.x + r1.x) + (r2.x + r3.x);                                  \
    float E2A = (r0.y + r1.y) + (r2.y + r3.y);                                  \
    float CRS = (r0.z + r1.z) + (r2.z + r3.z);                                  \
    bool  g0  = (E2C >= thrT);                                                  \
    float c_  = rnT1 * rcT;                                                     \
    float e2n = g0 ? fmaf(c_, fmaf(c_, E2C, -2.f * CRS), E2A) : E2A;            \
    bool  g1  = (e2n >= thrT1);                                                 \
    float gc  = g0 ? c_ : 0.f;                                                  \
    float eN0 = fmaf(-gc, errC0, eA0), eN1 = fmaf(-gc, errC1, eA1);             \
    float cf0 = g0 ? rc2T : 0.f, cf1 = g1 ? rcT1 : 0.f;                         \
    float d0 = fmaf(cf1, eN0, fmaf(cf0, errC0, p1a));                           \
    float d1 = fmaf(cf1, eN1, fmaf(cf0, errC1, p1b));                           \
    /* carries */                                                               \
    errP0 = errC0; errP1 = errC1; cuP = g0 ? rnT : 0.f;                         \
    errQ0 = eN0;   errQ1 = eN1;   cuQ = g1 ? rnT1 : 0.f;                        \
    errC0 = ks2.x - rnT2 * d0;                                                  \
    errC1 = ks2.y - rnT2 * d1;                                                  \
  }

    // Regions T = 0,2,...,252 (127). Buffer rotation (4 regs, period 2):
    //   parity0: update(B,C) load(A,B);  parity1: update(D,A) load(C,D)
    for (int tt = 0; tt < 252; tt += 4) {
        REGION2(tt,     kbB, kbC, kbA, kbB);
        REGION2(tt + 2, kbD, kbA, kbC, kbD);
    }
    REGION2(252, kbB, kbC, kbA, kbB);
#undef REGION2

    // ---- epilogue: apply updates for steps 252 (kbD), 253 (kbA); gate 254;
    //      readout = M_255 * k_255 = M_254*k_255 + g254*rc[254]*err_254 ----
    UPD(cuP, errP0, errP1, kbD)
    UPD(cuQ, errQ0, errQ1, kbA)
    {
        const float4* ks = shk4 + 255 * 32 + cq * 8;
        #pragma unroll
        for (int u = 0; u < 8; ++u) kbC[u] = ks[(u + cq) & 7];
    }
    float prea = 0.f, preb = 0.f;
    #pragma unroll
    for (int u = 0; u < 8; ++u) {
        prea = fma4(m0[u], kbC[u], prea);
        preb = fma4(m1[u], kbC[u], preb);
    }
    prea = quad_sum(prea); preb = quad_sum(preb);
    float e2p = (cq == 0) ? fmaf(errC0, errC0, errC1 * errC1) : 0.f;
    e2p = wave_sum(e2p);
    if (lane == 63) red4[4 + w] = make_float4(e2p, 0.f, 0.f, 0.f);  // parity-1 slots
    __syncthreads();
    {
        float e2t = (red4[4].x + red4[5].x) + (red4[6].x + red4[7].x);
        bool  g   = (e2t >= thr[254]);
        float cf  = g ? rc_[254] : 0.f;
        float d0  = fmaf(cf, errC0, prea);
        float d1  = fmaf(cf, errC1, preb);
        if (cq == 0)
            ((float2*)readout)[b * 64 + w * 16 + p] = make_float2(d0, d1);
    }
#undef UPD
}

// ---------------------------------------------------------------------------
// Kernel 3: out = (read @ Wr^T + br) @ Wo^T + bo.  (unchanged)
// ---------------------------------------------------------------------------
__global__ __launch_bounds__(256) void k_out(
    const float* __restrict__ readout,
    const float* __restrict__ Wr, const float* __restrict__ br,
    const float* __restrict__ Wo, const float* __restrict__ bo,
    float* __restrict__ out)
{
    __shared__ float sh_rd[128];
    __shared__ float sh_r2[128];
    const int b = blockIdx.x, tid = threadIdx.x;

    if (tid < 32) ((float4*)sh_rd)[tid] = ((const float4*)readout)[b * 32 + tid];
    __syncthreads();

    {
        int i = tid >> 1, h = tid & 1;
        const float4* Wr4 = (const float4*)Wr;
        const float4* rd4 = (const float4*)sh_rd;
        float s = 0.f;
        #pragma unroll
        for (int u = 0; u < 16; ++u) s = fma4(rd4[h * 16 + u], Wr4[i * 32 + h * 16 + u], s);
        s += __shfl_xor(s, 1);
        if (h == 0) sh_r2[i] = s + br[i];
    }
    __syncthreads();

    {
        const float4* Wo4 = (const float4*)Wo;
        const float4* r24 = (const float4*)sh_r2;
        float acc = bo[tid];
        #pragma unroll
        for (int u = 0; u < 32; ++u) acc = fma4(r24[u], Wo4[tid * 32 + u], acc);
        out[b * 256 + tid] = acc;
    }
}

// ---------------------------------------------------------------------------
extern "C" void kernel_launch(void* const* d_in, const int* in_sizes, int n_in,
                              void* d_out, int out_size, void* d_ws, size_t ws_size,
                              hipStream_t stream) {
    const int*   seq   = (const int*)  d_in[0];
    const float* embed = (const float*)d_in[1];
    const float* W1    = (const float*)d_in[2];
    const float* b1    = (const float*)d_in[3];
    const float* W2    = (const float*)d_in[4];
    const float* b2    = (const float*)d_in[5];
    const float* gamma = (const float*)d_in[6];
    const float* beta  = (const float*)d_in[7];
    const float* Wk    = (const float*)d_in[8];
    const float* Wr    = (const float*)d_in[9];
    const float* br    = (const float*)d_in[10];
    const float* Wo    = (const float*)d_in[11];
    const float* bo    = (const float*)d_in[12];

    float* Kbuf    = (float*)d_ws;                    // 32768 * 128 f32 = 16 MiB
    float* readout = Kbuf + (size_t)TOK_ * H_;        // 128 * 128 f32
    float* out     = (float*)d_out;

    // k_scan dynamic LDS: 128 KiB k-store + 4*256 f32 scalars + 2*4 float4 red
    const size_t scan_lds = 32768 * 4 + 4 * 256 * 4 + 8 * 16;   // 135200 B

    k_ffn <<<TOK_ / 64, 256, 0, stream>>>(seq, embed, W1, b1, W2, b2, gamma, beta, Wk, Kbuf);
    k_scan<<<B_,       256, scan_lds, stream>>>(Kbuf, readout);
    k_out <<<B_,       256, 0, stream>>>(readout, Wr, br, Wo, bo, out);
}

// Round 8
// 221.614 us; speedup vs baseline: 1.1241x; 1.1241x over previous
//
#include <hip/hip_runtime.h>
#include <math.h>

// Problem dims (fixed)
#define B_   128
#define L_   256
#define H_   128
#define H2_  256
#define VS_  256
#define TOK_ (B_ * L_)   // 32768

__device__ __forceinline__ float fma4(float4 a, float4 b, float acc) {
    acc = fmaf(a.x, b.x, acc);
    acc = fmaf(a.y, b.y, acc);
    acc = fmaf(a.z, b.z, acc);
    acc = fmaf(a.w, b.w, acc);
    return acc;
}

// ---------------- DPP cross-lane helpers (VALU-latency, no LDS) -------------
template <int CTRL>
__device__ __forceinline__ float dpp_add(float x) {
    int y = __builtin_amdgcn_update_dpp(0, __float_as_int(x), CTRL, 0xf, 0xf, true);
    return x + __int_as_float(y);
}
// Full 64-lane sum; total lands in lane 63.
__device__ __forceinline__ float wave_sum(float x) {
    x = dpp_add<0x111>(x);  // row_shr:1
    x = dpp_add<0x112>(x);  // row_shr:2
    x = dpp_add<0x114>(x);  // row_shr:4
    x = dpp_add<0x118>(x);  // row_shr:8
    x = dpp_add<0x142>(x);  // row_bcast:15
    x = dpp_add<0x143>(x);  // row_bcast:31
    return x;
}
// Sum over the 4 lanes of each quad (butterfly -> valid in all 4 lanes).
__device__ __forceinline__ float quad_sum(float x) {
    x = dpp_add<0xB1>(x);   // quad_perm [1,0,3,2]
    x = dpp_add<0x4E>(x);   // quad_perm [2,3,0,1]
    return x;
}

// LDS index swizzles for k_ffn (unchanged)
#define HIDX(row, c4) ((row) * 32 + ((c4) ^ (((row) >> 2) & 7)))
#define WIDX(oc, k4)  ((oc) * 16 + ((k4) ^ (((oc) >> 2) & 15)))
#define YIDX(row, y4) ((row) * 16 + ((y4) ^ (((row) >> 2) & 15)))

// ---------------------------------------------------------------------------
// Kernel 1: fused  h = embed[seq];  f = relu(h@W1^T+b1)@W2^T+b2;
//                  x = h+f;  hln = LN(x)*gamma+beta;  K = hln@Wk^T
// (unchanged from round 1)
// ---------------------------------------------------------------------------
__global__ __launch_bounds__(256, 2) void k_ffn(
    const int* __restrict__ seq, const float* __restrict__ embed,
    const float* __restrict__ W1, const float* __restrict__ b1,
    const float* __restrict__ W2, const float* __restrict__ b2,
    const float* __restrict__ gamma, const float* __restrict__ beta,
    const float* __restrict__ Wk, float* __restrict__ Kout)
{
    __shared__ float4 sh_h[64 * 32];
    __shared__ float4 sh_w[64 * 16];
    __shared__ float4 sh_y[64 * 16];

    const int tid  = threadIdx.x;
    const int tc   = tid & 15;
    const int tr   = tid >> 4;
    const int tok0 = blockIdx.x * 64;

    const float4* embed4 = (const float4*)embed;
    const float4* W1_4   = (const float4*)W1;
    const float4* W2_4   = (const float4*)W2;
    const float4* Wk_4   = (const float4*)Wk;
    const float4* b1_4   = (const float4*)b1;
    const float4* b2_4   = (const float4*)b2;
    const float4* g_4    = (const float4*)gamma;
    const float4* be_4   = (const float4*)beta;

    #pragma unroll
    for (int f = tid; f < 2048; f += 256) {
        int row = f >> 5, c4 = f & 31;
        int idx = seq[tok0 + row];
        sh_h[HIDX(row, c4)] = embed4[idx * 32 + c4];
    }
    __syncthreads();

    float xacc[4][2][4];
    #pragma unroll
    for (int i = 0; i < 4; ++i)
        #pragma unroll
        for (int xh = 0; xh < 2; ++xh)
            #pragma unroll
            for (int j = 0; j < 4; ++j) xacc[i][xh][j] = 0.f;

    for (int nt = 0; nt < 4; ++nt) {
        float acc1[4][4];
        #pragma unroll
        for (int i = 0; i < 4; ++i)
            #pragma unroll
            for (int j = 0; j < 4; ++j) acc1[i][j] = 0.f;

        for (int kt = 0; kt < 2; ++kt) {
            #pragma unroll
            for (int f = tid; f < 1024; f += 256) {
                int oc = f >> 4, k4 = f & 15;
                sh_w[WIDX(oc, k4)] = W1_4[(nt * 64 + oc) * 32 + kt * 16 + k4];
            }
            __syncthreads();
            #pragma unroll 4
            for (int k4i = 0; k4i < 16; ++k4i) {
                float4 a4[4], b4[4];
                #pragma unroll
                for (int i = 0; i < 4; ++i) a4[i] = sh_h[HIDX(tr * 4 + i, kt * 16 + k4i)];
                #pragma unroll
                for (int j = 0; j < 4; ++j) b4[j] = sh_w[WIDX(tc * 4 + j, k4i)];
                #pragma unroll
                for (int i = 0; i < 4; ++i)
                    #pragma unroll
                    for (int j = 0; j < 4; ++j) acc1[i][j] = fma4(a4[i], b4[j], acc1[i][j]);
            }
            __syncthreads();
        }
        {
            float4 bv = b1_4[nt * 16 + tc];
            #pragma unroll
            for (int i = 0; i < 4; ++i) {
                float4 y;
                y.x = fmaxf(acc1[i][0] + bv.x, 0.f);
                y.y = fmaxf(acc1[i][1] + bv.y, 0.f);
                y.z = fmaxf(acc1[i][2] + bv.z, 0.f);
                y.w = fmaxf(acc1[i][3] + bv.w, 0.f);
                sh_y[YIDX(tr * 4 + i, tc)] = y;
            }
        }
        __syncthreads();

        #pragma unroll
        for (int xh = 0; xh < 2; ++xh) {
            #pragma unroll
            for (int f = tid; f < 1024; f += 256) {
                int oc = f >> 4, y4 = f & 15;
                sh_w[WIDX(oc, y4)] = W2_4[(xh * 64 + oc) * 64 + nt * 16 + y4];
            }
            __syncthreads();
            #pragma unroll 4
            for (int y4i = 0; y4i < 16; ++y4i) {
                float4 a4[4], b4[4];
                #pragma unroll
                for (int i = 0; i < 4; ++i) a4[i] = sh_y[YIDX(tr * 4 + i, y4i)];
                #pragma unroll
                for (int j = 0; j < 4; ++j) b4[j] = sh_w[WIDX(tc * 4 + j, y4i)];
                #pragma unroll
                for (int i = 0; i < 4; ++i)
                    #pragma unroll
                    for (int j = 0; j < 4; ++j) xacc[i][xh][j] = fma4(a4[i], b4[j], xacc[i][xh][j]);
            }
            __syncthreads();
        }
    }

    #pragma unroll
    for (int xh = 0; xh < 2; ++xh) {
        float4 bv = b2_4[xh * 16 + tc];
        int c4 = xh * 16 + tc;
        #pragma unroll
        for (int i = 0; i < 4; ++i) {
            float4 h4 = sh_h[HIDX(tr * 4 + i, c4)];
            h4.x += xacc[i][xh][0] + bv.x;
            h4.y += xacc[i][xh][1] + bv.y;
            h4.z += xacc[i][xh][2] + bv.z;
            h4.w += xacc[i][xh][3] + bv.w;
            sh_h[HIDX(tr * 4 + i, c4)] = h4;
        }
    }
    __syncthreads();

    {
        int row = tid >> 2, q = tid & 3;
        float s = 0.f, s2 = 0.f;
        #pragma unroll
        for (int u = 0; u < 8; ++u) {
            float4 v = sh_h[HIDX(row, q * 8 + u)];
            s  += v.x + v.y + v.z + v.w;
            s2 += v.x * v.x + v.y * v.y + v.z * v.z + v.w * v.w;
        }
        s  += __shfl_xor(s, 1);  s  += __shfl_xor(s, 2);
        s2 += __shfl_xor(s2, 1); s2 += __shfl_xor(s2, 2);
        float mu   = s * (1.f / 128.f);
        float var  = s2 * (1.f / 128.f) - mu * mu;
        float rstd = 1.f / sqrtf(var + 1e-5f);
        #pragma unroll
        for (int u = 0; u < 8; ++u) {
            int c4 = q * 8 + u;
            float4 v  = sh_h[HIDX(row, c4)];
            float4 gv = g_4[c4], bev = be_4[c4];
            v.x = (v.x - mu) * rstd * gv.x + bev.x;
            v.y = (v.y - mu) * rstd * gv.y + bev.y;
            v.z = (v.z - mu) * rstd * gv.z + bev.z;
            v.w = (v.w - mu) * rstd * gv.w + bev.w;
            sh_h[HIDX(row, c4)] = v;
        }
    }
    __syncthreads();

    for (int ch = 0; ch < 2; ++ch) {
        float acc[4][4];
        #pragma unroll
        for (int i = 0; i < 4; ++i)
            #pragma unroll
            for (int j = 0; j < 4; ++j) acc[i][j] = 0.f;

        for (int kt = 0; kt < 2; ++kt) {
            #pragma unroll
            for (int f = tid; f < 1024; f += 256) {
                int oc = f >> 4, k4 = f & 15;
                sh_w[WIDX(oc, k4)] = Wk_4[(ch * 64 + oc) * 32 + kt * 16 + k4];
            }
            __syncthreads();
            #pragma unroll 4
            for (int k4i = 0; k4i < 16; ++k4i) {
                float4 a4[4], b4[4];
                #pragma unroll
                for (int i = 0; i < 4; ++i) a4[i] = sh_h[HIDX(tr * 4 + i, kt * 16 + k4i)];
                #pragma unroll
                for (int j = 0; j < 4; ++j) b4[j] = sh_w[WIDX(tc * 4 + j, k4i)];
                #pragma unroll
                for (int i = 0; i < 4; ++i)
                    #pragma unroll
                    for (int j = 0; j < 4; ++j) acc[i][j] = fma4(a4[i], b4[j], acc[i][j]);
            }
            __syncthreads();
        }
        #pragma unroll
        for (int i = 0; i < 4; ++i) {
            float4 o = make_float4(acc[i][0], acc[i][1], acc[i][2], acc[i][3]);
            ((float4*)Kout)[(tok0 + tr * 4 + i) * 32 + ch * 16 + tc] = o;
        }
    }
}

// ---------------------------------------------------------------------------
// Kernel 2: gated delta-rule scan — fused update+matvec, 512 threads.
//   Thread (w,lane): row = w*16 + (lane>>2), col chunk cq = lane&3 (32 cols,
//   labeling rotated by cq for conflict-free LDS reads). Per region t:
//     red-read gate_t -> a = g*rna[t]*err_t
//     fused loop: m[u] += a*k_t[u];  pre += m[u]*k_{t+1}[u]   (exact reference
//     recurrence — no correction term)
//     load k_{t+2} into the dead buffer; quad_sum(pre) -> err_{t+1};
//     wave_sum(e2) -> red write -> barrier.
//   2 k-buffers, parity rotation, all statically indexed.
// ---------------------------------------------------------------------------
__global__ __launch_bounds__(512) void k_scan(
    const float* __restrict__ Kbuf, float* __restrict__ readout)
{
    extern __shared__ float smem_f[];
    float4* shk4  = (float4*)smem_f;          // [256][32] float4 = 128 KiB
    float*  shkf  = smem_f;                   // same, scalar view
    float*  rna   = smem_f + 32768;           // [256] 1/max(||k_t||,eps)
    float*  thr   = rna + 256;                // [256] 0.16*||k_t||^2
    float*  red_f = thr + 256;                // [2][8] e2 partials

    const int tid  = threadIdx.x;
    const int lane = tid & 63;
    const int w    = tid >> 6;        // wave id 0..7
    const int cq   = lane & 3;        // col chunk 0..3 (32 cols each)
    const int row  = w * 16 + (lane >> 2);   // 0..127
    const int b    = blockIdx.x;
    const float4* K4 = (const float4*)Kbuf;
    const size_t base32 = (size_t)b * 256 * 32;

    // ---- prologue 1: stage ALL k vectors ----
    for (int f = tid; f < 8192; f += 512) shk4[f] = K4[base32 + f];
    __syncthreads();

    // ---- prologue 2: per-row norms (32 rows/pass, 16 threads per row) ----
    {
        int rr = tid >> 4, cc = tid & 15;
        for (int it = 0; it < 8; ++it) {
            int t = it * 32 + rr;
            float4 a0 = shk4[t * 32 + cc], a1 = shk4[t * 32 + 16 + cc];
            float n2p = fma4(a1, a1, fma4(a0, a0, 0.f));
            n2p += __shfl_xor(n2p, 1); n2p += __shfl_xor(n2p, 2);
            n2p += __shfl_xor(n2p, 4); n2p += __shfl_xor(n2p, 8);
            if (cc == 0) {
                rna[t] = 1.f / fmaxf(sqrtf(n2p), 1e-12f);
                thr[t] = 0.16f * n2p;
            }
        }
    }

    // ---- M row, k buffers, err_0 ----
    float4 m[8];
    #pragma unroll
    for (int u = 0; u < 8; ++u) m[u] = make_float4(0.f, 0.f, 0.f, 0.f);

    float4 kbE[8], kbO[8];
    {
        const float4* ks0 = shk4 + cq * 8;
        const float4* ks1 = shk4 + 32 + cq * 8;
        #pragma unroll
        for (int u = 0; u < 8; ++u) {
            kbE[u] = ks0[(u + cq) & 7];   // k_0
            kbO[u] = ks1[(u + cq) & 7];   // k_1
        }
    }
    float errR = shkf[row];               // err_0 = k_0[row]
    {
        float e2p = (cq == 0) ? errR * errR : 0.f;
        e2p = wave_sum(e2p);
        if (lane == 63) red_f[w] = e2p;   // parity-0 slots for region 0
    }
    __syncthreads();

#define REGION(T, KU, KM)                                                       \
  {                                                                             \
    const int t_ = (T);                                                         \
    float rnaT = rna[t_], rnaN = rna[t_ + 1], thrT = thr[t_];                   \
    float kselfN = shkf[(t_ + 1) * 128 + row];                                  \
    float4 ra = ((const float4*)red_f)[(t_ & 1) * 2];                           \
    float4 rb = ((const float4*)red_f)[(t_ & 1) * 2 + 1];                       \
    float E2 = ((ra.x + ra.y) + (ra.z + ra.w)) +                                \
               ((rb.x + rb.y) + (rb.z + rb.w));                                 \
    float a_ = (E2 >= thrT) ? rnaT * errR : 0.f;                                \
    float pre = 0.f;                                                            \
    _Pragma("unroll")                                                           \
    for (int u = 0; u < 8; ++u) {                                               \
      m[u].x = fmaf(a_, KU[u].x, m[u].x);                                       \
      m[u].y = fmaf(a_, KU[u].y, m[u].y);                                       \
      m[u].z = fmaf(a_, KU[u].z, m[u].z);                                       \
      m[u].w = fmaf(a_, KU[u].w, m[u].w);                                       \
      pre = fma4(m[u], KM[u], pre);                                             \
    }                                                                           \
    /* load k_{t+2} into KU (dead now); latency covered by reduce+barrier */    \
    {                                                                           \
      const float4* ks = shk4 + (t_ + 2) * 32 + cq * 8;                         \
      _Pragma("unroll")                                                         \
      for (int u = 0; u < 8; ++u) KU[u] = ks[(u + cq) & 7];                     \
    }                                                                           \
    pre = quad_sum(pre);                                                        \
    float errN = fmaf(-rnaN, pre, kselfN);                                      \
    float e2p = (cq == 0) ? errN * errN : 0.f;                                  \
    e2p = wave_sum(e2p);                                                        \
    if (lane == 63) red_f[((t_ + 1) & 1) * 8 + w] = e2p;                        \
    __syncthreads();                                                            \
    errR = errN;                                                                \
  }

    for (int tt = 0; tt < 254; tt += 2) {
        REGION(tt,     kbE, kbO);
        REGION(tt + 1, kbO, kbE);
    }
#undef REGION

    // ---- region 254 (last): gate_254, fused upd(k_254)+mv(k_255), readout ----
    {
        float rnaT = rna[254], thrT = thr[254];
        float4 ra = ((const float4*)red_f)[0];
        float4 rb = ((const float4*)red_f)[1];
        float E2 = ((ra.x + ra.y) + (ra.z + ra.w)) +
                   ((rb.x + rb.y) + (rb.z + rb.w));
        float a_ = (E2 >= thrT) ? rnaT * errR : 0.f;
        float pre = 0.f;
        #pragma unroll
        for (int u = 0; u < 8; ++u) {
            m[u].x = fmaf(a_, kbE[u].x, m[u].x);
            m[u].y = fmaf(a_, kbE[u].y, m[u].y);
            m[u].z = fmaf(a_, kbE[u].z, m[u].z);
            m[u].w = fmaf(a_, kbE[u].w, m[u].w);
            pre = fma4(m[u], kbO[u], pre);
        }
        pre = quad_sum(pre);
        if (cq == 0) readout[b * 128 + row] = pre;   // M_255 * k_255
    }
}

// ---------------------------------------------------------------------------
// Kernel 3: out = (read @ Wr^T + br) @ Wo^T + bo.  (unchanged)
// ---------------------------------------------------------------------------
__global__ __launch_bounds__(256) void k_out(
    const float* __restrict__ readout,
    const float* __restrict__ Wr, const float* __restrict__ br,
    const float* __restrict__ Wo, const float* __restrict__ bo,
    float* __restrict__ out)
{
    __shared__ float sh_rd[128];
    __shared__ float sh_r2[128];
    const int b = blockIdx.x, tid = threadIdx.x;

    if (tid < 32) ((float4*)sh_rd)[tid] = ((const float4*)readout)[b * 32 + tid];
    __syncthreads();

    {
        int i = tid >> 1, h = tid & 1;
        const float4* Wr4 = (const float4*)Wr;
        const float4* rd4 = (const float4*)sh_rd;
        float s = 0.f;
        #pragma unroll
        for (int u = 0; u < 16; ++u) s = fma4(rd4[h * 16 + u], Wr4[i * 32 + h * 16 + u], s);
        s += __shfl_xor(s, 1);
        if (h == 0) sh_r2[i] = s + br[i];
    }
    __syncthreads();

    {
        const float4* Wo4 = (const float4*)Wo;
        const float4* r24 = (const float4*)sh_r2;
        float acc = bo[tid];
        #pragma unroll
        for (int u = 0; u < 32; ++u) acc = fma4(r24[u], Wo4[tid * 32 + u], acc);
        out[b * 256 + tid] = acc;
    }
}

// ---------------------------------------------------------------------------
extern "C" void kernel_launch(void* const* d_in, const int* in_sizes, int n_in,
                              void* d_out, int out_size, void* d_ws, size_t ws_size,
                              hipStream_t stream) {
    const int*   seq   = (const int*)  d_in[0];
    const float* embed = (const float*)d_in[1];
    const float* W1    = (const float*)d_in[2];
    const float* b1    = (const float*)d_in[3];
    const float* W2    = (const float*)d_in[4];
    const float* b2    = (const float*)d_in[5];
    const float* gamma = (const float*)d_in[6];
    const float* beta  = (const float*)d_in[7];
    const float* Wk    = (const float*)d_in[8];
    const float* Wr    = (const float*)d_in[9];
    const float* br    = (const float*)d_in[10];
    const float* Wo    = (const float*)d_in[11];
    const float* bo    = (const float*)d_in[12];

    float* Kbuf    = (float*)d_ws;                    // 32768 * 128 f32 = 16 MiB
    float* readout = Kbuf + (size_t)TOK_ * H_;        // 128 * 128 f32
    float* out     = (float*)d_out;

    // k_scan dynamic LDS: 128 KiB k-store + rna/thr + red
    const size_t scan_lds = 32768 * 4 + 2 * 256 * 4 + 16 * 4;   // 133,184 B

    k_ffn <<<TOK_ / 64, 256, 0, stream>>>(seq, embed, W1, b1, W2, b2, gamma, beta, Wk, Kbuf);
    k_scan<<<B_,       512, scan_lds, stream>>>(Kbuf, readout);
    k_out <<<B_,       256, 0, stream>>>(readout, Wr, br, Wo, bo, out);
}

// Round 9
// 221.472 us; speedup vs baseline: 1.1248x; 1.0006x over previous
//
#include <hip/hip_runtime.h>
#include <math.h>

// Problem dims (fixed)
#define B_   128
#define L_   256
#define H_   128
#define H2_  256
#define VS_  256
#define TOK_ (B_ * L_)   // 32768

__device__ __forceinline__ float fma4(float4 a, float4 b, float acc) {
    acc = fmaf(a.x, b.x, acc);
    acc = fmaf(a.y, b.y, acc);
    acc = fmaf(a.z, b.z, acc);
    acc = fmaf(a.w, b.w, acc);
    return acc;
}

// ---------------- DPP cross-lane helpers (VALU-latency, no LDS) -------------
template <int CTRL>
__device__ __forceinline__ float dpp_add(float x) {
    int y = __builtin_amdgcn_update_dpp(0, __float_as_int(x), CTRL, 0xf, 0xf, true);
    return x + __int_as_float(y);
}
// Full 64-lane sum; total lands in lane 63.
__device__ __forceinline__ float wave_sum(float x) {
    x = dpp_add<0x111>(x);  // row_shr:1
    x = dpp_add<0x112>(x);  // row_shr:2
    x = dpp_add<0x114>(x);  // row_shr:4
    x = dpp_add<0x118>(x);  // row_shr:8
    x = dpp_add<0x142>(x);  // row_bcast:15
    x = dpp_add<0x143>(x);  // row_bcast:31
    return x;
}
// Sum over the 4 lanes of each quad (butterfly -> valid in all 4 lanes).
__device__ __forceinline__ float quad_sum(float x) {
    x = dpp_add<0xB1>(x);   // quad_perm [1,0,3,2]
    x = dpp_add<0x4E>(x);   // quad_perm [2,3,0,1]
    return x;
}

// LDS index swizzles for k_ffn (unchanged)
#define HIDX(row, c4) ((row) * 32 + ((c4) ^ (((row) >> 2) & 7)))
#define WIDX(oc, k4)  ((oc) * 16 + ((k4) ^ (((oc) >> 2) & 15)))
#define YIDX(row, y4) ((row) * 16 + ((y4) ^ (((row) >> 2) & 15)))

// ---------------------------------------------------------------------------
// Kernel 1: fused  h = embed[seq];  f = relu(h@W1^T+b1)@W2^T+b2;
//                  x = h+f;  hln = LN(x)*gamma+beta;  K = hln@Wk^T
// (unchanged from round 1)
// ---------------------------------------------------------------------------
__global__ __launch_bounds__(256, 2) void k_ffn(
    const int* __restrict__ seq, const float* __restrict__ embed,
    const float* __restrict__ W1, const float* __restrict__ b1,
    const float* __restrict__ W2, const float* __restrict__ b2,
    const float* __restrict__ gamma, const float* __restrict__ beta,
    const float* __restrict__ Wk, float* __restrict__ Kout)
{
    __shared__ float4 sh_h[64 * 32];
    __shared__ float4 sh_w[64 * 16];
    __shared__ float4 sh_y[64 * 16];

    const int tid  = threadIdx.x;
    const int tc   = tid & 15;
    const int tr   = tid >> 4;
    const int tok0 = blockIdx.x * 64;

    const float4* embed4 = (const float4*)embed;
    const float4* W1_4   = (const float4*)W1;
    const float4* W2_4   = (const float4*)W2;
    const float4* Wk_4   = (const float4*)Wk;
    const float4* b1_4   = (const float4*)b1;
    const float4* b2_4   = (const float4*)b2;
    const float4* g_4    = (const float4*)gamma;
    const float4* be_4   = (const float4*)beta;

    #pragma unroll
    for (int f = tid; f < 2048; f += 256) {
        int row = f >> 5, c4 = f & 31;
        int idx = seq[tok0 + row];
        sh_h[HIDX(row, c4)] = embed4[idx * 32 + c4];
    }
    __syncthreads();

    float xacc[4][2][4];
    #pragma unroll
    for (int i = 0; i < 4; ++i)
        #pragma unroll
        for (int xh = 0; xh < 2; ++xh)
            #pragma unroll
            for (int j = 0; j < 4; ++j) xacc[i][xh][j] = 0.f;

    for (int nt = 0; nt < 4; ++nt) {
        float acc1[4][4];
        #pragma unroll
        for (int i = 0; i < 4; ++i)
            #pragma unroll
            for (int j = 0; j < 4; ++j) acc1[i][j] = 0.f;

        for (int kt = 0; kt < 2; ++kt) {
            #pragma unroll
            for (int f = tid; f < 1024; f += 256) {
                int oc = f >> 4, k4 = f & 15;
                sh_w[WIDX(oc, k4)] = W1_4[(nt * 64 + oc) * 32 + kt * 16 + k4];
            }
            __syncthreads();
            #pragma unroll 4
            for (int k4i = 0; k4i < 16; ++k4i) {
                float4 a4[4], b4[4];
                #pragma unroll
                for (int i = 0; i < 4; ++i) a4[i] = sh_h[HIDX(tr * 4 + i, kt * 16 + k4i)];
                #pragma unroll
                for (int j = 0; j < 4; ++j) b4[j] = sh_w[WIDX(tc * 4 + j, k4i)];
                #pragma unroll
                for (int i = 0; i < 4; ++i)
                    #pragma unroll
                    for (int j = 0; j < 4; ++j) acc1[i][j] = fma4(a4[i], b4[j], acc1[i][j]);
            }
            __syncthreads();
        }
        {
            float4 bv = b1_4[nt * 16 + tc];
            #pragma unroll
            for (int i = 0; i < 4; ++i) {
                float4 y;
                y.x = fmaxf(acc1[i][0] + bv.x, 0.f);
                y.y = fmaxf(acc1[i][1] + bv.y, 0.f);
                y.z = fmaxf(acc1[i][2] + bv.z, 0.f);
                y.w = fmaxf(acc1[i][3] + bv.w, 0.f);
                sh_y[YIDX(tr * 4 + i, tc)] = y;
            }
        }
        __syncthreads();

        #pragma unroll
        for (int xh = 0; xh < 2; ++xh) {
            #pragma unroll
            for (int f = tid; f < 1024; f += 256) {
                int oc = f >> 4, y4 = f & 15;
                sh_w[WIDX(oc, y4)] = W2_4[(xh * 64 + oc) * 64 + nt * 16 + y4];
            }
            __syncthreads();
            #pragma unroll 4
            for (int y4i = 0; y4i < 16; ++y4i) {
                float4 a4[4], b4[4];
                #pragma unroll
                for (int i = 0; i < 4; ++i) a4[i] = sh_y[YIDX(tr * 4 + i, y4i)];
                #pragma unroll
                for (int j = 0; j < 4; ++j) b4[j] = sh_w[WIDX(tc * 4 + j, y4i)];
                #pragma unroll
                for (int i = 0; i < 4; ++i)
                    #pragma unroll
                    for (int j = 0; j < 4; ++j) xacc[i][xh][j] = fma4(a4[i], b4[j], xacc[i][xh][j]);
            }
            __syncthreads();
        }
    }

    #pragma unroll
    for (int xh = 0; xh < 2; ++xh) {
        float4 bv = b2_4[xh * 16 + tc];
        int c4 = xh * 16 + tc;
        #pragma unroll
        for (int i = 0; i < 4; ++i) {
            float4 h4 = sh_h[HIDX(tr * 4 + i, c4)];
            h4.x += xacc[i][xh][0] + bv.x;
            h4.y += xacc[i][xh][1] + bv.y;
            h4.z += xacc[i][xh][2] + bv.z;
            h4.w += xacc[i][xh][3] + bv.w;
            sh_h[HIDX(tr * 4 + i, c4)] = h4;
        }
    }
    __syncthreads();

    {
        int row = tid >> 2, q = tid & 3;
        float s = 0.f, s2 = 0.f;
        #pragma unroll
        for (int u = 0; u < 8; ++u) {
            float4 v = sh_h[HIDX(row, q * 8 + u)];
            s  += v.x + v.y + v.z + v.w;
            s2 += v.x * v.x + v.y * v.y + v.z * v.z + v.w * v.w;
        }
        s  += __shfl_xor(s, 1);  s  += __shfl_xor(s, 2);
        s2 += __shfl_xor(s2, 1); s2 += __shfl_xor(s2, 2);
        float mu   = s * (1.f / 128.f);
        float var  = s2 * (1.f / 128.f) - mu * mu;
        float rstd = 1.f / sqrtf(var + 1e-5f);
        #pragma unroll
        for (int u = 0; u < 8; ++u) {
            int c4 = q * 8 + u;
            float4 v  = sh_h[HIDX(row, c4)];
            float4 gv = g_4[c4], bev = be_4[c4];
            v.x = (v.x - mu) * rstd * gv.x + bev.x;
            v.y = (v.y - mu) * rstd * gv.y + bev.y;
            v.z = (v.z - mu) * rstd * gv.z + bev.z;
            v.w = (v.w - mu) * rstd * gv.w + bev.w;
            sh_h[HIDX(row, c4)] = v;
        }
    }
    __syncthreads();

    for (int ch = 0; ch < 2; ++ch) {
        float acc[4][4];
        #pragma unroll
        for (int i = 0; i < 4; ++i)
            #pragma unroll
            for (int j = 0; j < 4; ++j) acc[i][j] = 0.f;

        for (int kt = 0; kt < 2; ++kt) {
            #pragma unroll
            for (int f = tid; f < 1024; f += 256) {
                int oc = f >> 4, k4 = f & 15;
                sh_w[WIDX(oc, k4)] = Wk_4[(ch * 64 + oc) * 32 + kt * 16 + k4];
            }
            __syncthreads();
            #pragma unroll 4
            for (int k4i = 0; k4i < 16; ++k4i) {
                float4 a4[4], b4[4];
                #pragma unroll
                for (int i = 0; i < 4; ++i) a4[i] = sh_h[HIDX(tr * 4 + i, kt * 16 + k4i)];
                #pragma unroll
                for (int j = 0; j < 4; ++j) b4[j] = sh_w[WIDX(tc * 4 + j, k4i)];
                #pragma unroll
                for (int i = 0; i < 4; ++i)
                    #pragma unroll
                    for (int j = 0; j < 4; ++j) acc[i][j] = fma4(a4[i], b4[j], acc[i][j]);
            }
            __syncthreads();
        }
        #pragma unroll
        for (int i = 0; i < 4; ++i) {
            float4 o = make_float4(acc[i][0], acc[i][1], acc[i][2], acc[i][3]);
            ((float4*)Kout)[(tok0 + tr * 4 + i) * 32 + ch * 16 + tc] = o;
        }
    }
}

// ---------------------------------------------------------------------------
// Kernel 2: gated delta-rule scan — gate-decoupled matvec, 512 threads.
//   Per region t (entering with m = M_{t-1}, errR = err_t, e2(err_t) in LDS):
//     [red-read  ||  preM = M_{t-1}·k_{t+1} (gate-independent, issues at once)]
//     gate_t -> a = g·rna[t]·errR
//     pre = quad_sum(preM) + a·d01[t]      // EXACT: M_t·k_{t+1}, d01 = k_t·k_{t+1}
//     err_{t+1} = k_{t+1}[row] - rna[t+1]·pre ; e2 -> wave_sum -> LDS
//     deferred: m += a·k_t  and  k-buffer refill  (overlap the barrier)
//   One barrier/step; all register arrays statically indexed.
// ---------------------------------------------------------------------------
__global__ __launch_bounds__(512) void k_scan(
    const float* __restrict__ Kbuf, float* __restrict__ readout)
{
    extern __shared__ float smem_f[];
    float4* shk4  = (float4*)smem_f;          // [256][32] float4 = 128 KiB
    float*  shkf  = smem_f;                   // same, scalar view
    float*  rna   = smem_f + 32768;           // [256] 1/max(||k_t||,eps)
    float*  thr   = rna + 256;                // [256] 0.16*||k_t||^2
    float*  d01   = thr + 256;                // [256] k_t . k_{t+1} (raw)
    float*  red_f = d01 + 256;                // [2][8] e2 partials

    const int tid  = threadIdx.x;
    const int lane = tid & 63;
    const int w    = tid >> 6;        // wave id 0..7
    const int cq   = lane & 3;        // col chunk 0..3 (32 cols each)
    const int row  = w * 16 + (lane >> 2);   // 0..127
    const int b    = blockIdx.x;
    const float4* K4 = (const float4*)Kbuf;
    const size_t base32 = (size_t)b * 256 * 32;

    // ---- prologue 1: stage ALL k vectors ----
    for (int f = tid; f < 8192; f += 512) shk4[f] = K4[base32 + f];
    __syncthreads();

    // ---- prologue 2: per-row norms + neighbor dots (16 threads per row) ----
    {
        int rr = tid >> 4, cc = tid & 15;
        for (int it = 0; it < 8; ++it) {
            int t  = it * 32 + rr;
            int tn = (t < 255) ? t + 1 : 255;
            float4 a0 = shk4[t  * 32 + cc], a1 = shk4[t  * 32 + 16 + cc];
            float4 b0 = shk4[tn * 32 + cc], b1 = shk4[tn * 32 + 16 + cc];
            float n2p = fma4(a1, a1, fma4(a0, a0, 0.f));
            float cp  = fma4(a1, b1, fma4(a0, b0, 0.f));
            n2p += __shfl_xor(n2p, 1); n2p += __shfl_xor(n2p, 2);
            n2p += __shfl_xor(n2p, 4); n2p += __shfl_xor(n2p, 8);
            cp  += __shfl_xor(cp, 1);  cp  += __shfl_xor(cp, 2);
            cp  += __shfl_xor(cp, 4);  cp  += __shfl_xor(cp, 8);
            if (cc == 0) {
                rna[t] = 1.f / fmaxf(sqrtf(n2p), 1e-12f);
                thr[t] = 0.16f * n2p;
                d01[t] = cp;
            }
        }
    }

    // ---- M row slice, k buffers, err_0 ----
    float4 m[8];
    #pragma unroll
    for (int u = 0; u < 8; ++u) m[u] = make_float4(0.f, 0.f, 0.f, 0.f);

    float4 kbE[8], kbO[8];
    {
        const float4* ks0 = shk4 + cq * 8;
        const float4* ks1 = shk4 + 32 + cq * 8;
        #pragma unroll
        for (int u = 0; u < 8; ++u) {
            kbE[u] = ks0[(u + cq) & 7];   // k_0
            kbO[u] = ks1[(u + cq) & 7];   // k_1
        }
    }
    float errR = shkf[row];               // err_0 = k_0[row]
    {
        float e2p = (cq == 0) ? errR * errR : 0.f;
        e2p = wave_sum(e2p);
        if (lane == 63) red_f[w] = e2p;   // parity-0 slots for region 0
    }
    __syncthreads();

#define REGION(T, KU, KM)                                                       \
  {                                                                             \
    const int t_ = (T);                                                         \
    float rnaT = rna[t_], rnaN = rna[t_ + 1];                                   \
    float thrT = thr[t_], d01T = d01[t_];                                       \
    float kselfN = shkf[(t_ + 1) * 128 + row];                                  \
    float4 ra = ((const float4*)red_f)[(t_ & 1) * 2];                           \
    float4 rb = ((const float4*)red_f)[(t_ & 1) * 2 + 1];                       \
    /* gate-independent matvec with M_{t-1}: issues in parallel w/ red read */  \
    float pA = 0.f, pB = 0.f;                                                   \
    pA = fma4(m[0], KM[0], pA); pB = fma4(m[1], KM[1], pB);                     \
    pA = fma4(m[2], KM[2], pA); pB = fma4(m[3], KM[3], pB);                     \
    pA = fma4(m[4], KM[4], pA); pB = fma4(m[5], KM[5], pB);                     \
    pA = fma4(m[6], KM[6], pA); pB = fma4(m[7], KM[7], pB);                     \
    float preM = quad_sum(pA + pB);                                             \
    float E2 = ((ra.x + ra.y) + (ra.z + ra.w)) +                                \
               ((rb.x + rb.y) + (rb.z + rb.w));                                 \
    float a_ = (E2 >= thrT) ? rnaT * errR : 0.f;                                \
    float pre = fmaf(a_, d01T, preM);    /* = M_t · k_{t+1}, exact */           \
    float errN = fmaf(-rnaN, pre, kselfN);                                      \
    float e2p = (cq == 0) ? errN * errN : 0.f;                                  \
    e2p = wave_sum(e2p);                                                        \
    if (lane == 63) red_f[((t_ + 1) & 1) * 8 + w] = e2p;                        \
    /* deferred update m += a·k_t (overlaps barrier), then refill KU<-k_{t+2} */\
    _Pragma("unroll")                                                           \
    for (int u = 0; u < 8; ++u) {                                               \
      m[u].x = fmaf(a_, KU[u].x, m[u].x);                                       \
      m[u].y = fmaf(a_, KU[u].y, m[u].y);                                       \
      m[u].z = fmaf(a_, KU[u].z, m[u].z);                                       \
      m[u].w = fmaf(a_, KU[u].w, m[u].w);                                       \
    }                                                                           \
    {                                                                           \
      const float4* ks = shk4 + (t_ + 2) * 32 + cq * 8;                         \
      _Pragma("unroll")                                                         \
      for (int u = 0; u < 8; ++u) KU[u] = ks[(u + cq) & 7];                     \
    }                                                                           \
    __syncthreads();                                                            \
    errR = errN;                                                                \
  }

    // Regions 0..253: after region t, m = M_t, errR = err_{t+1}.
    for (int tt = 0; tt < 254; tt += 2) {
        REGION(tt,     kbE, kbO);
        REGION(tt + 1, kbO, kbE);
    }
#undef REGION

    // ---- epilogue: step 254 fused into readout.
    //      readout = M_254·k_255 = M_253·k_255 + a_254·(k_254·k_255) ----
    {
        float4 ra = ((const float4*)red_f)[0];   // parity (254&1)=0 slots
        float4 rb = ((const float4*)red_f)[1];
        float E2 = ((ra.x + ra.y) + (ra.z + ra.w)) +
                   ((rb.x + rb.y) + (rb.z + rb.w));
        float a_ = (E2 >= thr[254]) ? rna[254] * errR : 0.f;
        float pA = 0.f, pB = 0.f;
        pA = fma4(m[0], kbO[0], pA); pB = fma4(m[1], kbO[1], pB);
        pA = fma4(m[2], kbO[2], pA); pB = fma4(m[3], kbO[3], pB);
        pA = fma4(m[4], kbO[4], pA); pB = fma4(m[5], kbO[5], pB);
        pA = fma4(m[6], kbO[6], pA); pB = fma4(m[7], kbO[7], pB);
        float preM = quad_sum(pA + pB);
        float pre  = fmaf(a_, d01[254], preM);
        if (cq == 0) readout[b * 128 + row] = pre;
    }
}

// ---------------------------------------------------------------------------
// Kernel 3: out = (read @ Wr^T + br) @ Wo^T + bo.  (unchanged)
// ---------------------------------------------------------------------------
__global__ __launch_bounds__(256) void k_out(
    const float* __restrict__ readout,
    const float* __restrict__ Wr, const float* __restrict__ br,
    const float* __restrict__ Wo, const float* __restrict__ bo,
    float* __restrict__ out)
{
    __shared__ float sh_rd[128];
    __shared__ float sh_r2[128];
    const int b = blockIdx.x, tid = threadIdx.x;

    if (tid < 32) ((float4*)sh_rd)[tid] = ((const float4*)readout)[b * 32 + tid];
    __syncthreads();

    {
        int i = tid >> 1, h = tid & 1;
        const float4* Wr4 = (const float4*)Wr;
        const float4* rd4 = (const float4*)sh_rd;
        float s = 0.f;
        #pragma unroll
        for (int u = 0; u < 16; ++u) s = fma4(rd4[h * 16 + u], Wr4[i * 32 + h * 16 + u], s);
        s += __shfl_xor(s, 1);
        if (h == 0) sh_r2[i] = s + br[i];
    }
    __syncthreads();

    {
        const float4* Wo4 = (const float4*)Wo;
        const float4* r24 = (const float4*)sh_r2;
        float acc = bo[tid];
        #pragma unroll
        for (int u = 0; u < 32; ++u) acc = fma4(r24[u], Wo4[tid * 32 + u], acc);
        out[b * 256 + tid] = acc;
    }
}

// ---------------------------------------------------------------------------
extern "C" void kernel_launch(void* const* d_in, const int* in_sizes, int n_in,
                              void* d_out, int out_size, void* d_ws, size_t ws_size,
                              hipStream_t stream) {
    const int*   seq   = (const int*)  d_in[0];
    const float* embed = (const float*)d_in[1];
    const float* W1    = (const float*)d_in[2];
    const float* b1    = (const float*)d_in[3];
    const float* W2    = (const float*)d_in[4];
    const float* b2    = (const float*)d_in[5];
    const float* gamma = (const float*)d_in[6];
    const float* beta  = (const float*)d_in[7];
    const float* Wk    = (const float*)d_in[8];
    const float* Wr    = (const float*)d_in[9];
    const float* br    = (const float*)d_in[10];
    const float* Wo    = (const float*)d_in[11];
    const float* bo    = (const float*)d_in[12];

    float* Kbuf    = (float*)d_ws;                    // 32768 * 128 f32 = 16 MiB
    float* readout = Kbuf + (size_t)TOK_ * H_;        // 128 * 128 f32
    float* out     = (float*)d_out;

    // k_scan dynamic LDS: 128 KiB k-store + rna/thr/d01 + red
    const size_t scan_lds = 32768 * 4 + 3 * 256 * 4 + 16 * 4;   // 134,208 B

    k_ffn <<<TOK_ / 64, 256, 0, stream>>>(seq, embed, W1, b1, W2, b2, gamma, beta, Wk, Kbuf);
    k_scan<<<B_,       512, scan_lds, stream>>>(Kbuf, readout);
    k_out <<<B_,       256, 0, stream>>>(readout, Wr, br, Wo, bo, out);
}

// Round 10
// 214.324 us; speedup vs baseline: 1.1624x; 1.0334x over previous
//
#include <hip/hip_runtime.h>
#include <math.h>

// Problem dims (fixed)
#define B_   128
#define L_   256
#define H_   128
#define H2_  256
#define VS_  256
#define TOK_ (B_ * L_)   // 32768

__device__ __forceinline__ float fma4(float4 a, float4 b, float acc) {
    acc = fmaf(a.x, b.x, acc);
    acc = fmaf(a.y, b.y, acc);
    acc = fmaf(a.z, b.z, acc);
    acc = fmaf(a.w, b.w, acc);
    return acc;
}

// ---------------- DPP cross-lane helpers (VALU-latency, no LDS) -------------
template <int CTRL>
__device__ __forceinline__ float dpp_add(float x) {
    int y = __builtin_amdgcn_update_dpp(0, __float_as_int(x), CTRL, 0xf, 0xf, true);
    return x + __int_as_float(y);
}
// Full 64-lane sum; total lands in lane 63.
__device__ __forceinline__ float wave_sum(float x) {
    x = dpp_add<0x111>(x);  // row_shr:1
    x = dpp_add<0x112>(x);  // row_shr:2
    x = dpp_add<0x114>(x);  // row_shr:4
    x = dpp_add<0x118>(x);  // row_shr:8
    x = dpp_add<0x142>(x);  // row_bcast:15
    x = dpp_add<0x143>(x);  // row_bcast:31
    return x;
}
// Sum over the 4 lanes of each quad (butterfly -> valid in all 4 lanes).
__device__ __forceinline__ float quad_sum(float x) {
    x = dpp_add<0xB1>(x);   // quad_perm [1,0,3,2]
    x = dpp_add<0x4E>(x);   // quad_perm [2,3,0,1]
    return x;
}

// 16-byte async global->LDS DMA (dst must be wave-uniform).
__device__ __forceinline__ void gld_lds16(const float4* src, float4* dst) {
    __builtin_amdgcn_global_load_lds(
        (const __attribute__((address_space(1))) void*)src,
        (__attribute__((address_space(3))) void*)dst, 16, 0, 0);
}

// LDS index swizzles (float4-slot units)
#define HIDX(row, c4) ((row) * 32 + ((c4) ^ (((row) >> 2) & 7)))
#define WIDX(oc, k4)  ((oc) * 16 + ((k4) ^ (((oc) >> 2) & 15)))
#define YIDX(row, y4) ((row) * 16 + ((y4) ^ (((row) >> 2) & 15)))

// ---------------------------------------------------------------------------
// Kernel 1 v2: fused embed/FFN/LN/Kproj with double-buffered async W staging.
//   - W tiles (64x64 f32 = 16 KiB) staged via global_load_lds width=16 into
//     2 ping-pong buffers; tile p+1 issued right after phase p's barrier, so
//     the DMA has a full compute phase (~2300 cy) to land (counted by the
//     vmcnt(0) inside the next __syncthreads).
//   - Swizzled layout preserved by pre-swizzling the GLOBAL source address
//     (linear LDS dest + swizzle on read — rule #21 compliant).
//   - h-gather (embed[seq]) also via global_load_lds.
//   Dynamic LDS 80 KiB: sh_h 32K | w0 16K | w1 16K | sh_y 16K. 2 blocks/CU.
// ---------------------------------------------------------------------------
__global__ __launch_bounds__(256, 2) void k_ffn(
    const int* __restrict__ seq, const float* __restrict__ embed,
    const float* __restrict__ W1, const float* __restrict__ b1,
    const float* __restrict__ W2, const float* __restrict__ b2,
    const float* __restrict__ gamma, const float* __restrict__ beta,
    const float* __restrict__ Wk, float* __restrict__ Kout)
{
    extern __shared__ float4 dynls[];
    float4* sh_h  = dynls;           // 2048 slots
    float4* sh_w0 = dynls + 2048;    // 1024
    float4* sh_w1 = dynls + 3072;    // 1024
    float4* sh_y  = dynls + 4096;    // 1024

    const int tid  = threadIdx.x;
    const int lane = tid & 63;
    const int wv   = tid >> 6;
    const int tc   = tid & 15;
    const int tr   = tid >> 4;
    const int tok0 = blockIdx.x * 64;

    const float4* embed4 = (const float4*)embed;
    const float4* W1_4   = (const float4*)W1;
    const float4* W2_4   = (const float4*)W2;
    const float4* Wk_4   = (const float4*)Wk;
    const float4* b1_4   = (const float4*)b1;
    const float4* b2_4   = (const float4*)b2;
    const float4* g_4    = (const float4*)gamma;
    const float4* be_4   = (const float4*)beta;

    // Stage one 64x64 W tile into wbuf: linear LDS dest, pre-swizzled source.
    // slot s=(oc,k4'): element (oc, k4'^((oc>>2)&15))  ==> read via WIDX works.
#define STAGE_TILE(WBUF, WG, ROWB, STRIDE4, COLB4)                         \
    {                                                                      \
        _Pragma("unroll")                                                  \
        for (int it_ = 0; it_ < 4; ++it_) {                                \
            int slot_ = it_ * 256 + wv * 64 + lane;                        \
            int oc_ = slot_ >> 4, k4_ = slot_ & 15;                        \
            int sw_ = k4_ ^ ((oc_ >> 2) & 15);                             \
            gld_lds16(WG + (ROWB + oc_) * (STRIDE4) + (COLB4) + sw_,       \
                      (WBUF) + it_ * 256 + wv * 64);                       \
        }                                                                  \
    }

    // ---- prologue: seq idx loads, stage tile0 = W1(0,0), swizzled h-gather ----
    int idxv[8];
    #pragma unroll
    for (int it = 0; it < 8; ++it) {
        int slot = it * 256 + tid;
        idxv[it] = seq[tok0 + (slot >> 5)];
    }
    STAGE_TILE(sh_w0, W1_4, 0, 32, 0);
    #pragma unroll
    for (int it = 0; it < 8; ++it) {
        int slot = it * 256 + wv * 64 + lane;      // == it*256 + tid
        int row = slot >> 5, c4p = slot & 31;
        int sw = c4p ^ ((row >> 2) & 7);
        gld_lds16(embed4 + (size_t)idxv[it] * 32 + sw,
                  sh_h + it * 256 + wv * 64);
    }
    __syncthreads();   // drains gather + tile0 DMA

    float xacc[4][2][4];
    #pragma unroll
    for (int i = 0; i < 4; ++i)
        #pragma unroll
        for (int xh = 0; xh < 2; ++xh)
            #pragma unroll
            for (int j = 0; j < 4; ++j) xacc[i][xh][j] = 0.f;

    #pragma unroll
    for (int nt = 0; nt < 4; ++nt) {
        float acc1[4][4];
        #pragma unroll
        for (int i = 0; i < 4; ++i)
            #pragma unroll
            for (int j = 0; j < 4; ++j) acc1[i][j] = 0.f;

        #pragma unroll
        for (int kt = 0; kt < 2; ++kt) {
            const int p = 4 * nt + kt;
            if (p > 0) __syncthreads();            // tile p landed; prev phase done
            // stage tile p+1
            if (kt == 0) { STAGE_TILE(((p + 1) & 1) ? sh_w1 : sh_w0, W1_4, nt * 64, 32, 16); }
            else         { STAGE_TILE(((p + 1) & 1) ? sh_w1 : sh_w0, W2_4, 0,       64, nt * 16); }
            const float4* wb = (p & 1) ? sh_w1 : sh_w0;
            #pragma unroll 4
            for (int k4i = 0; k4i < 16; ++k4i) {
                float4 a4[4], b4[4];
                #pragma unroll
                for (int i = 0; i < 4; ++i) a4[i] = sh_h[HIDX(tr * 4 + i, kt * 16 + k4i)];
                #pragma unroll
                for (int j = 0; j < 4; ++j) b4[j] = wb[WIDX(tc * 4 + j, k4i)];
                #pragma unroll
                for (int i = 0; i < 4; ++i)
                    #pragma unroll
                    for (int j = 0; j < 4; ++j) acc1[i][j] = fma4(a4[i], b4[j], acc1[i][j]);
            }
        }
        // bias + relu -> sh_y (own slots; no pre-barrier needed)
        {
            float4 bv = b1_4[nt * 16 + tc];
            #pragma unroll
            for (int i = 0; i < 4; ++i) {
                float4 y;
                y.x = fmaxf(acc1[i][0] + bv.x, 0.f);
                y.y = fmaxf(acc1[i][1] + bv.y, 0.f);
                y.z = fmaxf(acc1[i][2] + bv.z, 0.f);
                y.w = fmaxf(acc1[i][3] + bv.w, 0.f);
                sh_y[YIDX(tr * 4 + i, tc)] = y;
            }
        }

        #pragma unroll
        for (int xh = 0; xh < 2; ++xh) {
            const int p = 4 * nt + 2 + xh;
            __syncthreads();                       // sh_y visible; tile p landed
            if (xh == 0)      { STAGE_TILE(((p + 1) & 1) ? sh_w1 : sh_w0, W2_4, 64, 64, nt * 16); }
            else if (nt < 3)  { STAGE_TILE(((p + 1) & 1) ? sh_w1 : sh_w0, W1_4, (nt + 1) * 64, 32, 0); }
            else              { STAGE_TILE(((p + 1) & 1) ? sh_w1 : sh_w0, Wk_4, 0, 32, 0); }
            const float4* wb = (p & 1) ? sh_w1 : sh_w0;
            #pragma unroll 4
            for (int y4i = 0; y4i < 16; ++y4i) {
                float4 a4[4], b4[4];
                #pragma unroll
                for (int i = 0; i < 4; ++i) a4[i] = sh_y[YIDX(tr * 4 + i, y4i)];
                #pragma unroll
                for (int j = 0; j < 4; ++j) b4[j] = wb[WIDX(tc * 4 + j, y4i)];
                #pragma unroll
                for (int i = 0; i < 4; ++i)
                    #pragma unroll
                    for (int j = 0; j < 4; ++j) xacc[i][xh][j] = fma4(a4[i], b4[j], xacc[i][xh][j]);
            }
        }
    }

    // ---- x = h + f + b2 (own slots; safe without barrier) ----
    #pragma unroll
    for (int xh = 0; xh < 2; ++xh) {
        float4 bv = b2_4[xh * 16 + tc];
        int c4 = xh * 16 + tc;
        #pragma unroll
        for (int i = 0; i < 4; ++i) {
            float4 h4 = sh_h[HIDX(tr * 4 + i, c4)];
            h4.x += xacc[i][xh][0] + bv.x;
            h4.y += xacc[i][xh][1] + bv.y;
            h4.z += xacc[i][xh][2] + bv.z;
            h4.w += xacc[i][xh][3] + bv.w;
            sh_h[HIDX(tr * 4 + i, c4)] = h4;
        }
    }
    __syncthreads();

    // ---- LayerNorm (4 threads per row) ----
    {
        int row = tid >> 2, q = tid & 3;
        float s = 0.f, s2 = 0.f;
        #pragma unroll
        for (int u = 0; u < 8; ++u) {
            float4 v = sh_h[HIDX(row, q * 8 + u)];
            s  += v.x + v.y + v.z + v.w;
            s2 += v.x * v.x + v.y * v.y + v.z * v.z + v.w * v.w;
        }
        s  += __shfl_xor(s, 1);  s  += __shfl_xor(s, 2);
        s2 += __shfl_xor(s2, 1); s2 += __shfl_xor(s2, 2);
        float mu   = s * (1.f / 128.f);
        float var  = s2 * (1.f / 128.f) - mu * mu;
        float rstd = 1.f / sqrtf(var + 1e-5f);
        #pragma unroll
        for (int u = 0; u < 8; ++u) {
            int c4 = q * 8 + u;
            float4 v  = sh_h[HIDX(row, c4)];
            float4 gv = g_4[c4], bev = be_4[c4];
            v.x = (v.x - mu) * rstd * gv.x + bev.x;
            v.y = (v.y - mu) * rstd * gv.y + bev.y;
            v.z = (v.z - mu) * rstd * gv.z + bev.z;
            v.w = (v.w - mu) * rstd * gv.w + bev.w;
            sh_h[HIDX(row, c4)] = v;
        }
    }

    // ---- K = hln @ Wk^T  (tiles 16..19) ----
    #pragma unroll
    for (int ch = 0; ch < 2; ++ch) {
        float acc[4][4];
        #pragma unroll
        for (int i = 0; i < 4; ++i)
            #pragma unroll
            for (int j = 0; j < 4; ++j) acc[i][j] = 0.f;

        #pragma unroll
        for (int kt = 0; kt < 2; ++kt) {
            const int p = 16 + 2 * ch + kt;
            __syncthreads();                       // LN visible / tile p landed
            if (p < 19) {
                int pn = p + 1;
                int chn = (pn - 16) >> 1, ktn = (pn - 16) & 1;
                STAGE_TILE((pn & 1) ? sh_w1 : sh_w0, Wk_4, chn * 64, 32, ktn * 16);
            }
            const float4* wb = (p & 1) ? sh_w1 : sh_w0;
            #pragma unroll 4
            for (int k4i = 0; k4i < 16; ++k4i) {
                float4 a4[4], b4[4];
                #pragma unroll
                for (int i = 0; i < 4; ++i) a4[i] = sh_h[HIDX(tr * 4 + i, kt * 16 + k4i)];
                #pragma unroll
                for (int j = 0; j < 4; ++j) b4[j] = wb[WIDX(tc * 4 + j, k4i)];
                #pragma unroll
                for (int i = 0; i < 4; ++i)
                    #pragma unroll
                    for (int j = 0; j < 4; ++j) acc[i][j] = fma4(a4[i], b4[j], acc[i][j]);
            }
        }
        #pragma unroll
        for (int i = 0; i < 4; ++i) {
            float4 o = make_float4(acc[i][0], acc[i][1], acc[i][2], acc[i][3]);
            ((float4*)Kout)[(tok0 + tr * 4 + i) * 32 + ch * 16 + tc] = o;
        }
    }
#undef STAGE_TILE
}

// ---------------------------------------------------------------------------
// Kernel 2: gated delta-rule scan — R9 structure + raw-barrier pipeline.
//   Changes vs R9: (a) __syncthreads -> ds_write(red) ; update ; refill ;
//   s_waitcnt lgkmcnt(8) ; s_barrier — the 8 refill reads stay in flight
//   ACROSS the barrier (write retired by the counted wait, in-order DS);
//   (b) e2 reduce shortened to 4 DPP stages (errN is quad-uniform, so
//   row_shr:4/8 pick one lane per quad exactly once, then bcast15/31).
// ---------------------------------------------------------------------------
__global__ __launch_bounds__(512) void k_scan(
    const float* __restrict__ Kbuf, float* __restrict__ readout)
{
    extern __shared__ float smem_f[];
    float4* shk4  = (float4*)smem_f;          // [256][32] float4 = 128 KiB
    float*  shkf  = smem_f;                   // same, scalar view
    float*  rna   = smem_f + 32768;           // [256] 1/max(||k_t||,eps)
    float*  thr   = rna + 256;                // [256] 0.16*||k_t||^2
    float*  d01   = thr + 256;                // [256] k_t . k_{t+1} (raw)
    float*  red_f = d01 + 256;                // [2][8] e2 partials

    const int tid  = threadIdx.x;
    const int lane = tid & 63;
    const int w    = tid >> 6;        // wave id 0..7
    const int cq   = lane & 3;        // col chunk 0..3 (32 cols each)
    const int row  = w * 16 + (lane >> 2);   // 0..127
    const int b    = blockIdx.x;
    const float4* K4 = (const float4*)Kbuf;
    const size_t base32 = (size_t)b * 256 * 32;

    // ---- prologue 1: stage ALL k vectors ----
    for (int f = tid; f < 8192; f += 512) shk4[f] = K4[base32 + f];
    __syncthreads();

    // ---- prologue 2: per-row norms + neighbor dots ----
    {
        int rr = tid >> 4, cc = tid & 15;
        for (int it = 0; it < 8; ++it) {
            int t  = it * 32 + rr;
            int tn = (t < 255) ? t + 1 : 255;
            float4 a0 = shk4[t  * 32 + cc], a1 = shk4[t  * 32 + 16 + cc];
            float4 b0 = shk4[tn * 32 + cc], b1 = shk4[tn * 32 + 16 + cc];
            float n2p = fma4(a1, a1, fma4(a0, a0, 0.f));
            float cp  = fma4(a1, b1, fma4(a0, b0, 0.f));
            n2p += __shfl_xor(n2p, 1); n2p += __shfl_xor(n2p, 2);
            n2p += __shfl_xor(n2p, 4); n2p += __shfl_xor(n2p, 8);
            cp  += __shfl_xor(cp, 1);  cp  += __shfl_xor(cp, 2);
            cp  += __shfl_xor(cp, 4);  cp  += __shfl_xor(cp, 8);
            if (cc == 0) {
                rna[t] = 1.f / fmaxf(sqrtf(n2p), 1e-12f);
                thr[t] = 0.16f * n2p;
                d01[t] = cp;
            }
        }
    }

    // ---- M row slice, k buffers, err_0 ----
    float4 m[8];
    #pragma unroll
    for (int u = 0; u < 8; ++u) m[u] = make_float4(0.f, 0.f, 0.f, 0.f);

    float4 kbE[8], kbO[8];
    {
        const float4* ks0 = shk4 + cq * 8;
        const float4* ks1 = shk4 + 32 + cq * 8;
        #pragma unroll
        for (int u = 0; u < 8; ++u) {
            kbE[u] = ks0[(u + cq) & 7];   // k_0
            kbO[u] = ks1[(u + cq) & 7];   // k_1
        }
    }
    float errR = shkf[row];               // err_0 = k_0[row]
    {
        float e2p = (cq == 0) ? errR * errR : 0.f;
        e2p = wave_sum(e2p);
        if (lane == 63) red_f[w] = e2p;   // parity-0 slots for region 0
    }
    __syncthreads();

#define REGION(T, KU, KM)                                                       \
  {                                                                             \
    const int t_ = (T);                                                         \
    float rnaT = rna[t_], rnaN = rna[t_ + 1];                                   \
    float thrT = thr[t_], d01T = d01[t_];                                       \
    float kselfN = shkf[(t_ + 1) * 128 + row];                                  \
    float4 ra = ((const float4*)red_f)[(t_ & 1) * 2];                           \
    float4 rb = ((const float4*)red_f)[(t_ & 1) * 2 + 1];                       \
    /* gate-independent matvec with M_{t-1}, overlaps the red read */           \
    float pA = 0.f, pB = 0.f;                                                   \
    pA = fma4(m[0], KM[0], pA); pB = fma4(m[1], KM[1], pB);                     \
    pA = fma4(m[2], KM[2], pA); pB = fma4(m[3], KM[3], pB);                     \
    pA = fma4(m[4], KM[4], pA); pB = fma4(m[5], KM[5], pB);                     \
    pA = fma4(m[6], KM[6], pA); pB = fma4(m[7], KM[7], pB);                     \
    float preM = quad_sum(pA + pB);                                             \
    float E2 = ((ra.x + ra.y) + (ra.z + ra.w)) +                                \
               ((rb.x + rb.y) + (rb.z + rb.w));                                 \
    float a_ = (E2 >= thrT) ? rnaT * errR : 0.f;                                \
    float pre = fmaf(a_, d01T, preM);    /* = M_t · k_{t+1}, exact */           \
    float errN = fmaf(-rnaN, pre, kselfN);                                      \
    /* errN is quad-uniform -> 4-stage reduce picks one lane per quad */        \
    float e2p = errN * errN;                                                    \
    e2p = dpp_add<0x114>(e2p);   /* row_shr:4  */                               \
    e2p = dpp_add<0x118>(e2p);   /* row_shr:8  */                               \
    e2p = dpp_add<0x142>(e2p);   /* row_bcast:15 */                             \
    e2p = dpp_add<0x143>(e2p);   /* row_bcast:31 -> lane63 total */             \
    if (lane == 63) red_f[((t_ + 1) & 1) * 8 + w] = e2p;                        \
    __builtin_amdgcn_sched_barrier(0);                                          \
    /* deferred update + refill: issued AFTER the red write (in-order DS) */    \
    _Pragma("unroll")                                                           \
    for (int u = 0; u < 8; ++u) {                                               \
      m[u].x = fmaf(a_, KU[u].x, m[u].x);                                       \
      m[u].y = fmaf(a_, KU[u].y, m[u].y);                                       \
      m[u].z = fmaf(a_, KU[u].z, m[u].z);                                       \
      m[u].w = fmaf(a_, KU[u].w, m[u].w);                                       \
    }                                                                           \
    {                                                                           \
      const float4* ks = shk4 + (t_ + 2) * 32 + cq * 8;                         \
      _Pragma("unroll")                                                         \
      for (int u = 0; u < 8; ++u) KU[u] = ks[(u + cq) & 7];                     \
    }                                                                           \
    __builtin_amdgcn_sched_barrier(0);                                          \
    /* write(1)+reads(8)=9 outstanding; lgkmcnt(8) retires the write only —    \
       the refill reads stay in flight ACROSS the barrier */                    \
    asm volatile("s_waitcnt lgkmcnt(8)" ::: "memory");                          \
    __builtin_amdgcn_sched_barrier(0);                                          \
    __builtin_amdgcn_s_barrier();                                               \
    errR = errN;                                                                \
  }

    // Regions 0..253: after region t, m = M_t, errR = err_{t+1}.
    for (int tt = 0; tt < 254; tt += 2) {
        REGION(tt,     kbE, kbO);
        REGION(tt + 1, kbO, kbE);
    }
#undef REGION

    // ---- epilogue: step 254 fused into readout.
    //      readout = M_254·k_255 = M_253·k_255 + a_254·(k_254·k_255) ----
    {
        float4 ra = ((const float4*)red_f)[0];   // parity (254&1)=0 slots
        float4 rb = ((const float4*)red_f)[1];
        float E2 = ((ra.x + ra.y) + (ra.z + ra.w)) +
                   ((rb.x + rb.y) + (rb.z + rb.w));
        float a_ = (E2 >= thr[254]) ? rna[254] * errR : 0.f;
        float pA = 0.f, pB = 0.f;
        pA = fma4(m[0], kbO[0], pA); pB = fma4(m[1], kbO[1], pB);
        pA = fma4(m[2], kbO[2], pA); pB = fma4(m[3], kbO[3], pB);
        pA = fma4(m[4], kbO[4], pA); pB = fma4(m[5], kbO[5], pB);
        pA = fma4(m[6], kbO[6], pA); pB = fma4(m[7], kbO[7], pB);
        float preM = quad_sum(pA + pB);
        float pre  = fmaf(a_, d01[254], preM);
        if (cq == 0) readout[b * 128 + row] = pre;
    }
}

// ---------------------------------------------------------------------------
// Kernel 3: out = (read @ Wr^T + br) @ Wo^T + bo.  (unchanged)
// ---------------------------------------------------------------------------
__global__ __launch_bounds__(256) void k_out(
    const float* __restrict__ readout,
    const float* __restrict__ Wr, const float* __restrict__ br,
    const float* __restrict__ Wo, const float* __restrict__ bo,
    float* __restrict__ out)
{
    __shared__ float sh_rd[128];
    __shared__ float sh_r2[128];
    const int b = blockIdx.x, tid = threadIdx.x;

    if (tid < 32) ((float4*)sh_rd)[tid] = ((const float4*)readout)[b * 32 + tid];
    __syncthreads();

    {
        int i = tid >> 1, h = tid & 1;
        const float4* Wr4 = (const float4*)Wr;
        const float4* rd4 = (const float4*)sh_rd;
        float s = 0.f;
        #pragma unroll
        for (int u = 0; u < 16; ++u) s = fma4(rd4[h * 16 + u], Wr4[i * 32 + h * 16 + u], s);
        s += __shfl_xor(s, 1);
        if (h == 0) sh_r2[i] = s + br[i];
    }
    __syncthreads();

    {
        const float4* Wo4 = (const float4*)Wo;
        const float4* r24 = (const float4*)sh_r2;
        float acc = bo[tid];
        #pragma unroll
        for (int u = 0; u < 32; ++u) acc = fma4(r24[u], Wo4[tid * 32 + u], acc);
        out[b * 256 + tid] = acc;
    }
}

// ---------------------------------------------------------------------------
extern "C" void kernel_launch(void* const* d_in, const int* in_sizes, int n_in,
                              void* d_out, int out_size, void* d_ws, size_t ws_size,
                              hipStream_t stream) {
    const int*   seq   = (const int*)  d_in[0];
    const float* embed = (const float*)d_in[1];
    const float* W1    = (const float*)d_in[2];
    const float* b1    = (const float*)d_in[3];
    const float* W2    = (const float*)d_in[4];
    const float* b2    = (const float*)d_in[5];
    const float* gamma = (const float*)d_in[6];
    const float* beta  = (const float*)d_in[7];
    const float* Wk    = (const float*)d_in[8];
    const float* Wr    = (const float*)d_in[9];
    const float* br    = (const float*)d_in[10];
    const float* Wo    = (const float*)d_in[11];
    const float* bo    = (const float*)d_in[12];

    float* Kbuf    = (float*)d_ws;                    // 32768 * 128 f32 = 16 MiB
    float* readout = Kbuf + (size_t)TOK_ * H_;        // 128 * 128 f32
    float* out     = (float*)d_out;

    const size_t ffn_lds  = 5120 * 16;                          // 80 KiB
    const size_t scan_lds = 32768 * 4 + 3 * 256 * 4 + 16 * 4;   // 134,208 B

    k_ffn <<<TOK_ / 64, 256, ffn_lds, stream>>>(seq, embed, W1, b1, W2, b2, gamma, beta, Wk, Kbuf);
    k_scan<<<B_,       512, scan_lds, stream>>>(Kbuf, readout);
    k_out <<<B_,       256, 0, stream>>>(readout, Wr, br, Wo, bo, out);
}

// Round 11
// 163.560 us; speedup vs baseline: 1.5231x; 1.3104x over previous
//
#include <hip/hip_runtime.h>
#include <math.h>

// Problem dims (fixed)
#define B_   128
#define L_   256
#define H_   128
#define H2_  256
#define VS_  256
#define TOK_ (B_ * L_)   // 32768

__device__ __forceinline__ float fma4(float4 a, float4 b, float acc) {
    acc = fmaf(a.x, b.x, acc);
    acc = fmaf(a.y, b.y, acc);
    acc = fmaf(a.z, b.z, acc);
    acc = fmaf(a.w, b.w, acc);
    return acc;
}

// ---------------- DPP cross-lane helpers (VALU-latency, no LDS) -------------
template <int CTRL>
__device__ __forceinline__ float dpp_add(float x) {
    int y = __builtin_amdgcn_update_dpp(0, __float_as_int(x), CTRL, 0xf, 0xf, true);
    return x + __int_as_float(y);
}
// Full 64-lane sum; total lands in lane 63.
__device__ __forceinline__ float wave_sum(float x) {
    x = dpp_add<0x111>(x);  // row_shr:1
    x = dpp_add<0x112>(x);  // row_shr:2
    x = dpp_add<0x114>(x);  // row_shr:4
    x = dpp_add<0x118>(x);  // row_shr:8
    x = dpp_add<0x142>(x);  // row_bcast:15
    x = dpp_add<0x143>(x);  // row_bcast:31
    return x;
}
// Sum over the 4 lanes of each quad (butterfly -> valid in all 4 lanes).
__device__ __forceinline__ float quad_sum(float x) {
    x = dpp_add<0xB1>(x);   // quad_perm [1,0,3,2]
    x = dpp_add<0x4E>(x);   // quad_perm [2,3,0,1]
    return x;
}

// ---------------------------------------------------------------------------
// Kernel 1 (NEW): per-VOCAB fused FFN.
//   Key insight: seq in [0,256) and the embed->FFN->LN->Kproj pipeline is
//   per-token with no cross-token coupling => only 256 distinct outputs.
//   F[v] = Wk-proj( LN( embed[v] + FFN(embed[v]) ) ), F: 256 x 128.
//   64 blocks x 4 vocab rows; ONE WAVE PER ROW (all phases wave-local).
//   W read straight from global (256 KB total, L2-hot); h/y staged in LDS.
// ---------------------------------------------------------------------------
__global__ __launch_bounds__(256) void k_vffn(
    const float* __restrict__ embed,
    const float* __restrict__ W1, const float* __restrict__ b1,
    const float* __restrict__ W2, const float* __restrict__ b2,
    const float* __restrict__ gamma, const float* __restrict__ beta,
    const float* __restrict__ Wk, float* __restrict__ Fout)
{
    __shared__ float sh_h[4][128];   // per-wave h row (then x, then hln)
    __shared__ float sh_y[4][256];   // per-wave relu(y1) row

    const int tid  = threadIdx.x;
    const int lane = tid & 63;
    const int r    = tid >> 6;            // wave id = local vocab row
    const int v    = blockIdx.x * 4 + r;  // vocab id 0..255

    const float4* embed4 = (const float4*)embed;
    const float4* W1_4   = (const float4*)W1;
    const float4* W2_4   = (const float4*)W2;
    const float4* Wk_4   = (const float4*)Wk;

    // ---- h = embed[v] -> LDS ----
    if (lane < 32)
        *(float4*)&sh_h[r][lane * 4] = embed4[v * 32 + lane];
    __syncthreads();

    // ---- GEMM1: y1[j] = relu(b1[j] + h . W1[j,:]), j = jj*64 + lane ----
    #pragma unroll
    for (int jj = 0; jj < 4; ++jj) {
        int j = jj * 64 + lane;
        const float4* wrow = W1_4 + j * 32;
        float acc = 0.f;
        #pragma unroll
        for (int c4 = 0; c4 < 32; ++c4)
            acc = fma4(*(const float4*)&sh_h[r][c4 * 4], wrow[c4], acc);
        sh_y[r][j] = fmaxf(acc + b1[j], 0.f);
    }
    __syncthreads();

    // ---- GEMM2 + residual: x[c] = h[c] + y1 . W2[c,:] + b2[c] ----
    float xv[4];
    #pragma unroll
    for (int cc = 0; cc < 4; ++cc) {
        int c  = cc * 32 + (lane & 31);
        int hf = lane >> 5;               // j-half 0/1
        const float4* wrow = W2_4 + c * 64 + hf * 32;
        float acc = 0.f;
        #pragma unroll
        for (int j4 = 0; j4 < 32; ++j4)
            acc = fma4(*(const float4*)&sh_y[r][(hf * 32 + j4) * 4], wrow[j4], acc);
        acc += __shfl_xor(acc, 32);       // combine halves (valid in all lanes)
        xv[cc] = acc;
    }
    if (lane < 32) {
        #pragma unroll
        for (int cc = 0; cc < 4; ++cc) {
            int c = cc * 32 + lane;
            sh_h[r][c] = sh_h[r][c] + xv[cc] + b2[c];
        }
    }
    __syncthreads();

    // ---- LayerNorm over 128 (one wave per row; lane owns 2 elems) ----
    {
        float2 x2 = *(const float2*)&sh_h[r][lane * 2];
        float s  = x2.x + x2.y;
        float s2 = x2.x * x2.x + x2.y * x2.y;
        s  += __shfl_xor(s, 1);  s  += __shfl_xor(s, 2);  s  += __shfl_xor(s, 4);
        s  += __shfl_xor(s, 8);  s  += __shfl_xor(s, 16); s  += __shfl_xor(s, 32);
        s2 += __shfl_xor(s2, 1); s2 += __shfl_xor(s2, 2); s2 += __shfl_xor(s2, 4);
        s2 += __shfl_xor(s2, 8); s2 += __shfl_xor(s2, 16); s2 += __shfl_xor(s2, 32);
        float mu   = s * (1.f / 128.f);
        float var  = s2 * (1.f / 128.f) - mu * mu;
        float rstd = 1.f / sqrtf(var + 1e-5f);
        float2 g2  = *(const float2*)&gamma[lane * 2];
        float2 be2 = *(const float2*)&beta[lane * 2];
        float2 o;
        o.x = (x2.x - mu) * rstd * g2.x + be2.x;
        o.y = (x2.y - mu) * rstd * g2.y + be2.y;
        *(float2*)&sh_h[r][lane * 2] = o;
    }
    __syncthreads();

    // ---- GEMM3: F[v][k] = hln . Wk[k,:], k = kk*64 + lane ----
    #pragma unroll
    for (int kk = 0; kk < 2; ++kk) {
        int k = kk * 64 + lane;
        const float4* wrow = Wk_4 + k * 32;
        float acc = 0.f;
        #pragma unroll
        for (int c4 = 0; c4 < 32; ++c4)
            acc = fma4(*(const float4*)&sh_h[r][c4 * 4], wrow[c4], acc);
        Fout[v * 128 + k] = acc;
    }
}

// ---------------------------------------------------------------------------
// Kernel 2: gated delta-rule scan — R10 structure; prologue now GATHERS the
//   256 k-vectors from the 128 KB F table via seq (L2-resident) instead of
//   streaming a 16 MB Kbuf. Everything else identical to R10.
// ---------------------------------------------------------------------------
__global__ __launch_bounds__(512) void k_scan(
    const int* __restrict__ seq, const float* __restrict__ Fbuf,
    float* __restrict__ readout)
{
    extern __shared__ float smem_f[];
    float4* shk4  = (float4*)smem_f;          // [256][32] float4 = 128 KiB
    float*  shkf  = smem_f;                   // same, scalar view
    float*  rna   = smem_f + 32768;           // [256] 1/max(||k_t||,eps)
    float*  thr   = rna + 256;                // [256] 0.16*||k_t||^2
    float*  d01   = thr + 256;                // [256] k_t . k_{t+1} (raw)
    float*  red_f = d01 + 256;                // [2][8] e2 partials

    const int tid  = threadIdx.x;
    const int lane = tid & 63;
    const int w    = tid >> 6;        // wave id 0..7
    const int cq   = lane & 3;        // col chunk 0..3 (32 cols each)
    const int row  = w * 16 + (lane >> 2);   // 0..127
    const int b    = blockIdx.x;
    const float4* F4 = (const float4*)Fbuf;
    const int* seqb = seq + b * 256;

    // ---- prologue 1: gather all 256 k vectors from F via seq ----
    for (int f = tid; f < 8192; f += 512) {
        int t = f >> 5, c = f & 31;
        shk4[f] = F4[(size_t)seqb[t] * 32 + c];
    }
    __syncthreads();

    // ---- prologue 2: per-row norms + neighbor dots ----
    {
        int rr = tid >> 4, cc = tid & 15;
        for (int it = 0; it < 8; ++it) {
            int t  = it * 32 + rr;
            int tn = (t < 255) ? t + 1 : 255;
            float4 a0 = shk4[t  * 32 + cc], a1 = shk4[t  * 32 + 16 + cc];
            float4 b0 = shk4[tn * 32 + cc], b1 = shk4[tn * 32 + 16 + cc];
            float n2p = fma4(a1, a1, fma4(a0, a0, 0.f));
            float cp  = fma4(a1, b1, fma4(a0, b0, 0.f));
            n2p += __shfl_xor(n2p, 1); n2p += __shfl_xor(n2p, 2);
            n2p += __shfl_xor(n2p, 4); n2p += __shfl_xor(n2p, 8);
            cp  += __shfl_xor(cp, 1);  cp  += __shfl_xor(cp, 2);
            cp  += __shfl_xor(cp, 4);  cp  += __shfl_xor(cp, 8);
            if (cc == 0) {
                rna[t] = 1.f / fmaxf(sqrtf(n2p), 1e-12f);
                thr[t] = 0.16f * n2p;
                d01[t] = cp;
            }
        }
    }

    // ---- M row slice, k buffers, err_0 ----
    float4 m[8];
    #pragma unroll
    for (int u = 0; u < 8; ++u) m[u] = make_float4(0.f, 0.f, 0.f, 0.f);

    float4 kbE[8], kbO[8];
    {
        const float4* ks0 = shk4 + cq * 8;
        const float4* ks1 = shk4 + 32 + cq * 8;
        #pragma unroll
        for (int u = 0; u < 8; ++u) {
            kbE[u] = ks0[(u + cq) & 7];   // k_0
            kbO[u] = ks1[(u + cq) & 7];   // k_1
        }
    }
    float errR = shkf[row];               // err_0 = k_0[row]
    {
        float e2p = (cq == 0) ? errR * errR : 0.f;
        e2p = wave_sum(e2p);
        if (lane == 63) red_f[w] = e2p;   // parity-0 slots for region 0
    }
    __syncthreads();

#define REGION(T, KU, KM)                                                       \
  {                                                                             \
    const int t_ = (T);                                                         \
    float rnaT = rna[t_], rnaN = rna[t_ + 1];                                   \
    float thrT = thr[t_], d01T = d01[t_];                                       \
    float kselfN = shkf[(t_ + 1) * 128 + row];                                  \
    float4 ra = ((const float4*)red_f)[(t_ & 1) * 2];                           \
    float4 rb = ((const float4*)red_f)[(t_ & 1) * 2 + 1];                       \
    /* gate-independent matvec with M_{t-1}, overlaps the red read */           \
    float pA = 0.f, pB = 0.f;                                                   \
    pA = fma4(m[0], KM[0], pA); pB = fma4(m[1], KM[1], pB);                     \
    pA = fma4(m[2], KM[2], pA); pB = fma4(m[3], KM[3], pB);                     \
    pA = fma4(m[4], KM[4], pA); pB = fma4(m[5], KM[5], pB);                     \
    pA = fma4(m[6], KM[6], pA); pB = fma4(m[7], KM[7], pB);                     \
    float preM = quad_sum(pA + pB);                                             \
    float E2 = ((ra.x + ra.y) + (ra.z + ra.w)) +                                \
               ((rb.x + rb.y) + (rb.z + rb.w));                                 \
    float a_ = (E2 >= thrT) ? rnaT * errR : 0.f;                                \
    float pre = fmaf(a_, d01T, preM);    /* = M_t · k_{t+1}, exact */           \
    float errN = fmaf(-rnaN, pre, kselfN);                                      \
    /* errN is quad-uniform -> 4-stage reduce picks one lane per quad */        \
    float e2p = errN * errN;                                                    \
    e2p = dpp_add<0x114>(e2p);   /* row_shr:4  */                               \
    e2p = dpp_add<0x118>(e2p);   /* row_shr:8  */                               \
    e2p = dpp_add<0x142>(e2p);   /* row_bcast:15 */                             \
    e2p = dpp_add<0x143>(e2p);   /* row_bcast:31 -> lane63 total */             \
    if (lane == 63) red_f[((t_ + 1) & 1) * 8 + w] = e2p;                        \
    __builtin_amdgcn_sched_barrier(0);                                          \
    /* deferred update + refill: issued AFTER the red write (in-order DS) */    \
    _Pragma("unroll")                                                           \
    for (int u = 0; u < 8; ++u) {                                               \
      m[u].x = fmaf(a_, KU[u].x, m[u].x);                                       \
      m[u].y = fmaf(a_, KU[u].y, m[u].y);                                       \
      m[u].z = fmaf(a_, KU[u].z, m[u].z);                                       \
      m[u].w = fmaf(a_, KU[u].w, m[u].w);                                       \
    }                                                                           \
    {                                                                           \
      const float4* ks = shk4 + (t_ + 2) * 32 + cq * 8;                         \
      _Pragma("unroll")                                                         \
      for (int u = 0; u < 8; ++u) KU[u] = ks[(u + cq) & 7];                     \
    }                                                                           \
    __builtin_amdgcn_sched_barrier(0);                                          \
    /* write(1)+reads(8)=9 outstanding; lgkmcnt(8) retires the write only —    \
       the refill reads stay in flight ACROSS the barrier */                    \
    asm volatile("s_waitcnt lgkmcnt(8)" ::: "memory");                          \
    __builtin_amdgcn_sched_barrier(0);                                          \
    __builtin_amdgcn_s_barrier();                                               \
    errR = errN;                                                                \
  }

    // Regions 0..253: after region t, m = M_t, errR = err_{t+1}.
    for (int tt = 0; tt < 254; tt += 2) {
        REGION(tt,     kbE, kbO);
        REGION(tt + 1, kbO, kbE);
    }
#undef REGION

    // ---- epilogue: step 254 fused into readout.
    //      readout = M_254·k_255 = M_253·k_255 + a_254·(k_254·k_255) ----
    {
        float4 ra = ((const float4*)red_f)[0];   // parity (254&1)=0 slots
        float4 rb = ((const float4*)red_f)[1];
        float E2 = ((ra.x + ra.y) + (ra.z + ra.w)) +
                   ((rb.x + rb.y) + (rb.z + rb.w));
        float a_ = (E2 >= thr[254]) ? rna[254] * errR : 0.f;
        float pA = 0.f, pB = 0.f;
        pA = fma4(m[0], kbO[0], pA); pB = fma4(m[1], kbO[1], pB);
        pA = fma4(m[2], kbO[2], pA); pB = fma4(m[3], kbO[3], pB);
        pA = fma4(m[4], kbO[4], pA); pB = fma4(m[5], kbO[5], pB);
        pA = fma4(m[6], kbO[6], pA); pB = fma4(m[7], kbO[7], pB);
        float preM = quad_sum(pA + pB);
        float pre  = fmaf(a_, d01[254], preM);
        if (cq == 0) readout[b * 128 + row] = pre;
    }
}

// ---------------------------------------------------------------------------
// Kernel 3: out = (read @ Wr^T + br) @ Wo^T + bo.  (unchanged)
// ---------------------------------------------------------------------------
__global__ __launch_bounds__(256) void k_out(
    const float* __restrict__ readout,
    const float* __restrict__ Wr, const float* __restrict__ br,
    const float* __restrict__ Wo, const float* __restrict__ bo,
    float* __restrict__ out)
{
    __shared__ float sh_rd[128];
    __shared__ float sh_r2[128];
    const int b = blockIdx.x, tid = threadIdx.x;

    if (tid < 32) ((float4*)sh_rd)[tid] = ((const float4*)readout)[b * 32 + tid];
    __syncthreads();

    {
        int i = tid >> 1, h = tid & 1;
        const float4* Wr4 = (const float4*)Wr;
        const float4* rd4 = (const float4*)sh_rd;
        float s = 0.f;
        #pragma unroll
        for (int u = 0; u < 16; ++u) s = fma4(rd4[h * 16 + u], Wr4[i * 32 + h * 16 + u], s);
        s += __shfl_xor(s, 1);
        if (h == 0) sh_r2[i] = s + br[i];
    }
    __syncthreads();

    {
        const float4* Wo4 = (const float4*)Wo;
        const float4* r24 = (const float4*)sh_r2;
        float acc = bo[tid];
        #pragma unroll
        for (int u = 0; u < 32; ++u) acc = fma4(r24[u], Wo4[tid * 32 + u], acc);
        out[b * 256 + tid] = acc;
    }
}

// ---------------------------------------------------------------------------
extern "C" void kernel_launch(void* const* d_in, const int* in_sizes, int n_in,
                              void* d_out, int out_size, void* d_ws, size_t ws_size,
                              hipStream_t stream) {
    const int*   seq   = (const int*)  d_in[0];
    const float* embed = (const float*)d_in[1];
    const float* W1    = (const float*)d_in[2];
    const float* b1    = (const float*)d_in[3];
    const float* W2    = (const float*)d_in[4];
    const float* b2    = (const float*)d_in[5];
    const float* gamma = (const float*)d_in[6];
    const float* beta  = (const float*)d_in[7];
    const float* Wk    = (const float*)d_in[8];
    const float* Wr    = (const float*)d_in[9];
    const float* br    = (const float*)d_in[10];
    const float* Wo    = (const float*)d_in[11];
    const float* bo    = (const float*)d_in[12];

    float* Fbuf    = (float*)d_ws;                    // 256 * 128 f32 = 128 KiB
    float* readout = Fbuf + (size_t)VS_ * H_;         // 128 * 128 f32
    float* out     = (float*)d_out;

    const size_t scan_lds = 32768 * 4 + 3 * 256 * 4 + 16 * 4;   // 134,208 B

    k_vffn<<<VS_ / 4, 256, 0, stream>>>(embed, W1, b1, W2, b2, gamma, beta, Wk, Fbuf);
    k_scan<<<B_,      512, scan_lds, stream>>>(seq, Fbuf, readout);
    k_out <<<B_,      256, 0, stream>>>(readout, Wr, br, Wo, bo, out);
}